// Round 6
// baseline (355.834 us; speedup 1.0000x reference)
//
#include <hip/hip_runtime.h>
#include <hip/hip_bf16.h>
#include <math.h>

#define H 128
#define RBF 50
#define CUTF 5.0f
#define PIF 3.14159265358979323846f
#define QT 1024                       // filter table intervals (QT+1 knots)

// ---------------------------------------------------------------------------
__global__ __launch_bounds__(256) void init_x_kernel(
    const int* __restrict__ atype, const float* __restrict__ emb,
    float* __restrict__ x, int Nn)
{
    int idx = blockIdx.x * blockDim.x + threadIdx.x;
    if (idx * 4 >= Nn * H) return;
    int n = idx >> 5;
    int c = (idx & 31) * 4;
    const float4 v = *(const float4*)(emb + atype[n] * H + c);
    *(float4*)(x + n * H + c) = v;
}

// pos4[n] = {x,y,z,0} — makes the edge_prep gather a single dwordx4
__global__ __launch_bounds__(256) void pos_pad_kernel(
    const float* __restrict__ pos, float4* __restrict__ pos4, int Nn)
{
    int n = blockIdx.x * 256 + threadIdx.x;
    if (n < Nn)
        pos4[n] = make_float4(pos[3 * n], pos[3 * n + 1], pos[3 * n + 2], 0.0f);
}

// ---------------------------------------------------------------------------
// Compact edges with d < CUT; flag src/dst atoms. One edge per thread,
// float4 position gathers, ballot compaction (1 atomic / 64 edges).
__global__ __launch_bounds__(256) void edge_prep_kernel(
    const float4* __restrict__ pos4, const int* __restrict__ ei, int E,
    int* __restrict__ cnt, int* __restrict__ asrc, int* __restrict__ adst,
    float* __restrict__ ad, int* __restrict__ is_src, int* __restrict__ is_dst)
{
    const int lane = threadIdx.x & 63;
    const int e = blockIdx.x * 256 + threadIdx.x;
    bool act = false;
    int s = 0, t = 0;
    float d = 0.0f;
    if (e < E) {
        s = ei[e]; t = ei[E + e];
        float4 ps = pos4[s], pt = pos4[t];
        float dx = ps.x - pt.x, dy = ps.y - pt.y, dz = ps.z - pt.z;
        d = sqrtf(dx * dx + dy * dy + dz * dz + 1e-12f);
        act = (d < CUTF);
    }
    unsigned long long b = __ballot(act);
    int tot = __popcll(b);
    int base = 0;
    if (lane == 0 && tot) base = atomicAdd(cnt, tot);
    base = __shfl(base, 0, 64);
    if (act) {
        const unsigned long long ltm = ((unsigned long long)1 << lane) - 1;
        int p = base + (int)__popcll(b & ltm);
        asrc[p] = s; adst[p] = t; ad[p] = d;
        is_src[s] = 1; is_dst[t] = 1;
    }
}

// ---------------------------------------------------------------------------
__global__ __launch_bounds__(256) void compact_atoms_kernel(
    const int* __restrict__ is_src, const int* __restrict__ is_dst, int Nn,
    int* __restrict__ cnt4,
    int* __restrict__ src_list, int* __restrict__ dst_list, int* __restrict__ nondst_list)
{
    int n = blockIdx.x * 256 + threadIdx.x;
    int lane = threadIdx.x & 63;
    bool vs = false, vd = false, vn = false;
    if (n < Nn) { vs = is_src[n] != 0; vd = is_dst[n] != 0; vn = !vd; }
    const unsigned long long ltm = ((unsigned long long)1 << lane) - 1;
    {
        unsigned long long b = __ballot(vs);
        int tot = __popcll(b); int base = 0;
        if (lane == 0 && tot) base = atomicAdd(cnt4 + 1, tot);
        base = __shfl(base, 0, 64);
        if (vs) src_list[base + (int)__popcll(b & ltm)] = n;
    }
    {
        unsigned long long b = __ballot(vd);
        int tot = __popcll(b); int base = 0;
        if (lane == 0 && tot) base = atomicAdd(cnt4 + 2, tot);
        base = __shfl(base, 0, 64);
        if (vd) dst_list[base + (int)__popcll(b & ltm)] = n;
    }
    {
        unsigned long long b = __ballot(vn);
        int tot = __popcll(b); int base = 0;
        if (lane == 0 && tot) base = atomicAdd(cnt4 + 3, tot);
        base = __shfl(base, 0, 64);
        if (vn) nondst_list[base + (int)__popcll(b & ltm)] = n;
    }
}

// ---------------------------------------------------------------------------
// Filter table + cvec, one wave per task.
//  wid < 2*(QT+1): tab[blk][q][:] = (tanh(rbf(d_q)@fw1+fb1)@fw2 + fb2)*cenv(d_q)
//  wid >= 2*(QT+1): cvec[blk][:] = tanh(lin2b_blk)@blkw_blk + blkb_blk
__global__ __launch_bounds__(256) void filter_table_kernel(
    const float* __restrict__ fw1, const float* __restrict__ fb1,
    const float* __restrict__ fw2, const float* __restrict__ fb2,
    const float* __restrict__ lin2b, const float* __restrict__ blkw,
    const float* __restrict__ blkb,
    float* __restrict__ tab, float* __restrict__ cvec)
{
    const int lane = threadIdx.x & 63;
    const int wid = (blockIdx.x * blockDim.x + threadIdx.x) >> 6;
    const int ntab = 2 * (QT + 1);
    if (wid >= ntab + 2) return;
    const int h0 = lane, h1 = lane + 64;

    if (wid >= ntab) {
        // cvec task
        const int blk = wid - ntab;
        const float* bwp = blkw + (size_t)blk * H * H;
        float t0 = tanhf(lin2b[blk * H + h0]);
        float t1 = tanhf(lin2b[blk * H + h1]);
        float a0 = blkb[blk * H + h0], a1 = blkb[blk * H + h1];
        #pragma unroll 8
        for (int k = 0; k < 64; ++k) {
            float bb = __shfl(t0, k, 64);
            a0 = fmaf(bb, bwp[k * H + h0], a0);
            a1 = fmaf(bb, bwp[k * H + h1], a1);
        }
        #pragma unroll 8
        for (int k = 0; k < 64; ++k) {
            float bb = __shfl(t1, k, 64);
            a0 = fmaf(bb, bwp[(64 + k) * H + h0], a0);
            a1 = fmaf(bb, bwp[(64 + k) * H + h1], a1);
        }
        cvec[blk * H + h0] = a0;
        cvec[blk * H + h1] = a1;
        return;
    }

    const int blk = wid / (QT + 1);
    const int q = wid - blk * (QT + 1);
    const float d = (float)q * (CUTF / (float)QT);

    const float* f1 = fw1 + (size_t)blk * RBF * H;
    const float* f2 = fw2 + (size_t)blk * H * H;
    const float step  = CUTF / 49.0f;
    const float coeff = -0.5f / (step * step);

    float cenv = (d < CUTF) ? 0.5f * (cosf(d * (PIF / CUTF)) + 1.0f) : 0.0f;

    float t0 = fb1[blk * H + h0], t1 = fb1[blk * H + h1];
    #pragma unroll
    for (int r = 0; r < RBF; ++r) {
        float u = d - (float)r * step;
        float rb = expf(coeff * u * u);
        t0 = fmaf(rb, f1[r * H + h0], t0);
        t1 = fmaf(rb, f1[r * H + h1], t1);
    }
    t0 = tanhf(t0); t1 = tanhf(t1);

    float w0 = fb2[blk * H + h0], w1v = fb2[blk * H + h1];
    #pragma unroll 8
    for (int k = 0; k < 64; ++k) {
        float bb = __shfl(t0, k, 64);
        w0  = fmaf(bb, f2[k * H + h0], w0);
        w1v = fmaf(bb, f2[k * H + h1], w1v);
    }
    #pragma unroll 8
    for (int k = 0; k < 64; ++k) {
        float bb = __shfl(t1, k, 64);
        w0  = fmaf(bb, f2[(64 + k) * H + h0], w0);
        w1v = fmaf(bb, f2[(64 + k) * H + h1], w1v);
    }
    float* row = tab + ((size_t)blk * (QT + 1) + q) * H;
    row[h0] = w0 * cenv;
    row[h1] = w1v * cenv;
}

// ---------------------------------------------------------------------------
// Per-edge scatter: W = lerp(table, d); msg = W * h[src]; atomicAdd agg[dst].
__global__ __launch_bounds__(256) void edge_scatter_kernel(
    const int* __restrict__ cnt,
    const int* __restrict__ asrc, const int* __restrict__ adst,
    const float* __restrict__ ad, const float* __restrict__ tab,
    const float* __restrict__ hbuf, float* __restrict__ agg)
{
    const int lane = threadIdx.x & 63;
    const int wid = (blockIdx.x * blockDim.x + threadIdx.x) >> 6;
    const int nw  = (gridDim.x * blockDim.x) >> 6;
    const int count = *cnt;
    const float scale = (float)QT / CUTF;

    for (int i = wid; i < count; i += nw) {
        int s = asrc[i], t = adst[i];
        float p = ad[i] * scale;
        int i0 = (int)p;
        if (i0 > QT - 1) i0 = QT - 1;
        float f = p - (float)i0;
        const float* r0 = tab + (size_t)i0 * H;
        float wl = fmaf(f, r0[H + lane] - r0[lane], r0[lane]);
        float wh = fmaf(f, r0[H + 64 + lane] - r0[64 + lane], r0[64 + lane]);
        float m0 = hbuf[(size_t)s * H + lane] * wl;
        float m1 = hbuf[(size_t)s * H + 64 + lane] * wh;
        atomicAdd(agg + (size_t)t * H + lane, m0);
        atomicAdd(agg + (size_t)t * H + 64 + lane, m1);
    }
}

// ---------------------------------------------------------------------------
// Role-split launch:
//  blocks [0, GB):       C[rows[i]] = A[rows[i]] @ W        (32-row tiles)
//  blocks [GB, GB+ZB):   zero zbuf rows in zrows
#define GB 512
#define ZB 128
__global__ __launch_bounds__(256) void gemm_rows_zero_kernel(
    const float* __restrict__ A, const float* __restrict__ W,
    float* __restrict__ C,
    const int* __restrict__ rows, const int* __restrict__ cntp,
    float* __restrict__ zbuf, const int* __restrict__ zrows,
    const int* __restrict__ zcntp)
{
    __shared__ float As[32][36];
    __shared__ float Ws[32][128];
    __shared__ int rlist[32];

    const int tid = threadIdx.x;

    if (blockIdx.x >= GB) {
        // zero role
        int zcnt = *zcntp;
        int total = zcnt * 32;
        for (int idx = (blockIdx.x - GB) * 256 + tid; idx < total; idx += ZB * 256) {
            int row = idx >> 5, c = (idx & 31) << 2;
            int r = zrows[row];
            *(float4*)(zbuf + (size_t)r * H + c) = make_float4(0.f, 0.f, 0.f, 0.f);
        }
        return;
    }

    const int cnt = *cntp;
    const int r0 = (tid >> 4) * 2;
    const int c0 = (tid & 15) * 4;

    for (int tile = blockIdx.x; tile * 32 < cnt; tile += GB) {
        __syncthreads();
        if (tid < 32) {
            int idx = tile * 32 + tid;
            rlist[tid] = (idx < cnt) ? rows[idx] : -1;
        }
        __syncthreads();

        float acc[2][8];
        #pragma unroll
        for (int j = 0; j < 2; ++j)
            #pragma unroll
            for (int c = 0; c < 8; ++c) acc[j][c] = 0.f;

        for (int kc = 0; kc < H; kc += 32) {
            {
                int lr = tid >> 3;
                int kk = (tid & 7) * 4;
                int r = rlist[lr];
                float4 v = make_float4(0.f, 0.f, 0.f, 0.f);
                if (r >= 0) v = *(const float4*)(A + (size_t)r * H + kc + kk);
                *(float4*)&As[lr][kk] = v;
            }
            {
                int wr = tid >> 5;
                int wc = (tid & 31) * 4;
                #pragma unroll
                for (int p = 0; p < 4; ++p) {
                    int row = wr + p * 8;
                    *(float4*)&Ws[row][wc] = *(const float4*)(W + (size_t)(kc + row) * H + wc);
                }
            }
            __syncthreads();
            #pragma unroll
            for (int k = 0; k < 32; k += 4) {
                float a_[2][4];
                #pragma unroll
                for (int j = 0; j < 2; ++j)
                    *(float4*)a_[j] = *(const float4*)&As[r0 + j][k];
                #pragma unroll
                for (int kk = 0; kk < 4; ++kk) {
                    float4 wlo = *(const float4*)&Ws[k + kk][c0];
                    float4 whi = *(const float4*)&Ws[k + kk][c0 + 64];
                    float w_[8] = {wlo.x, wlo.y, wlo.z, wlo.w, whi.x, whi.y, whi.z, whi.w};
                    #pragma unroll
                    for (int j = 0; j < 2; ++j)
                        #pragma unroll
                        for (int c = 0; c < 8; ++c)
                            acc[j][c] = fmaf(a_[j][kk], w_[c], acc[j][c]);
                }
            }
            __syncthreads();
        }
        #pragma unroll
        for (int j = 0; j < 2; ++j) {
            int r = rlist[r0 + j];
            if (r < 0) continue;
            #pragma unroll
            for (int hh = 0; hh < 2; ++hh) {
                int cb = c0 + hh * 64;
                *(float4*)(C + (size_t)r * H + cb) = make_float4(
                    acc[j][hh * 4 + 0], acc[j][hh * 4 + 1],
                    acc[j][hh * 4 + 2], acc[j][hh * 4 + 3]);
            }
        }
    }
}

// ---------------------------------------------------------------------------
// Role-split x update:
//  blocks [0, UB):      x[r] += tanh(agg[r]@l2w + l2b)@bw + bb   (dst rows)
//  blocks [UB, UB+AB):  x[r] += cvec                              (nondst rows)
#define UB 512
#define AB 256
__global__ __launch_bounds__(256) void update_x_kernel(
    const float* __restrict__ agg, const float* __restrict__ l2w,
    const float* __restrict__ l2b, const float* __restrict__ bw,
    const float* __restrict__ bb, float* __restrict__ x,
    const int* __restrict__ rows, const int* __restrict__ cntp,
    const int* __restrict__ nrows, const int* __restrict__ ncntp,
    const float* __restrict__ cvec)
{
    __shared__ float As[32][36];
    __shared__ float Ws[32][128];
    __shared__ float Tl[32][132];
    __shared__ int rlist[32];

    const int tid = threadIdx.x;

    if (blockIdx.x >= UB) {
        int ncnt = *ncntp;
        int total = ncnt * 32;
        for (int idx = (blockIdx.x - UB) * 256 + tid; idx < total; idx += AB * 256) {
            int row = idx >> 5, c = (idx & 31) << 2;
            int r = nrows[row];
            float4 v = *(const float4*)(x + (size_t)r * H + c);
            float4 cv = *(const float4*)(cvec + c);
            v.x += cv.x; v.y += cv.y; v.z += cv.z; v.w += cv.w;
            *(float4*)(x + (size_t)r * H + c) = v;
        }
        return;
    }

    const int cnt = *cntp;
    const int r0 = (tid >> 4) * 2;
    const int c0 = (tid & 15) * 4;

    for (int tile = blockIdx.x; tile * 32 < cnt; tile += UB) {
        __syncthreads();
        if (tid < 32) {
            int idx = tile * 32 + tid;
            rlist[tid] = (idx < cnt) ? rows[idx] : -1;
        }
        __syncthreads();

        // phase A: T = tanh(agg @ l2w + l2b)
        float acc[2][8];
        #pragma unroll
        for (int j = 0; j < 2; ++j)
            #pragma unroll
            for (int c = 0; c < 8; ++c) acc[j][c] = 0.f;

        for (int kc = 0; kc < H; kc += 32) {
            {
                int lr = tid >> 3;
                int kk = (tid & 7) * 4;
                int r = rlist[lr];
                float4 v = make_float4(0.f, 0.f, 0.f, 0.f);
                if (r >= 0) v = *(const float4*)(agg + (size_t)r * H + kc + kk);
                *(float4*)&As[lr][kk] = v;
            }
            {
                int wr = tid >> 5;
                int wc = (tid & 31) * 4;
                #pragma unroll
                for (int p = 0; p < 4; ++p) {
                    int row = wr + p * 8;
                    *(float4*)&Ws[row][wc] = *(const float4*)(l2w + (size_t)(kc + row) * H + wc);
                }
            }
            __syncthreads();
            #pragma unroll
            for (int k = 0; k < 32; k += 4) {
                float a_[2][4];
                #pragma unroll
                for (int j = 0; j < 2; ++j)
                    *(float4*)a_[j] = *(const float4*)&As[r0 + j][k];
                #pragma unroll
                for (int kk = 0; kk < 4; ++kk) {
                    float4 wlo = *(const float4*)&Ws[k + kk][c0];
                    float4 whi = *(const float4*)&Ws[k + kk][c0 + 64];
                    float w_[8] = {wlo.x, wlo.y, wlo.z, wlo.w, whi.x, whi.y, whi.z, whi.w};
                    #pragma unroll
                    for (int j = 0; j < 2; ++j)
                        #pragma unroll
                        for (int c = 0; c < 8; ++c)
                            acc[j][c] = fmaf(a_[j][kk], w_[c], acc[j][c]);
                }
            }
            __syncthreads();
        }
        #pragma unroll
        for (int j = 0; j < 2; ++j) {
            float4 lo, hi;
            lo.x = tanhf(acc[j][0] + l2b[c0]);      lo.y = tanhf(acc[j][1] + l2b[c0 + 1]);
            lo.z = tanhf(acc[j][2] + l2b[c0 + 2]);  lo.w = tanhf(acc[j][3] + l2b[c0 + 3]);
            hi.x = tanhf(acc[j][4] + l2b[c0 + 64]); hi.y = tanhf(acc[j][5] + l2b[c0 + 65]);
            hi.z = tanhf(acc[j][6] + l2b[c0 + 66]); hi.w = tanhf(acc[j][7] + l2b[c0 + 67]);
            *(float4*)&Tl[r0 + j][c0] = lo;
            *(float4*)&Tl[r0 + j][c0 + 64] = hi;
        }

        // phase B: x[r] += T @ bw + bb
        float acc2[2][8];
        #pragma unroll
        for (int j = 0; j < 2; ++j)
            #pragma unroll
            for (int c = 0; c < 8; ++c) acc2[j][c] = 0.f;

        for (int kc = 0; kc < H; kc += 32) {
            __syncthreads();
            {
                int wr = tid >> 5;
                int wc = (tid & 31) * 4;
                #pragma unroll
                for (int p = 0; p < 4; ++p) {
                    int row = wr + p * 8;
                    *(float4*)&Ws[row][wc] = *(const float4*)(bw + (size_t)(kc + row) * H + wc);
                }
            }
            __syncthreads();
            #pragma unroll
            for (int k = 0; k < 32; k += 4) {
                float a_[2][4];
                #pragma unroll
                for (int j = 0; j < 2; ++j)
                    *(float4*)a_[j] = *(const float4*)&Tl[r0 + j][kc + k];
                #pragma unroll
                for (int kk = 0; kk < 4; ++kk) {
                    float4 wlo = *(const float4*)&Ws[k + kk][c0];
                    float4 whi = *(const float4*)&Ws[k + kk][c0 + 64];
                    float w_[8] = {wlo.x, wlo.y, wlo.z, wlo.w, whi.x, whi.y, whi.z, whi.w};
                    #pragma unroll
                    for (int j = 0; j < 2; ++j)
                        #pragma unroll
                        for (int c = 0; c < 8; ++c)
                            acc2[j][c] = fmaf(a_[j][kk], w_[c], acc2[j][c]);
                }
            }
        }
        #pragma unroll
        for (int j = 0; j < 2; ++j) {
            int r = rlist[r0 + j];
            if (r < 0) continue;
            #pragma unroll
            for (int hh = 0; hh < 2; ++hh) {
                int cb = c0 + hh * 64;
                float4 xv = *(const float4*)(x + (size_t)r * H + cb);
                xv.x += acc2[j][hh * 4 + 0] + bb[cb];
                xv.y += acc2[j][hh * 4 + 1] + bb[cb + 1];
                xv.z += acc2[j][hh * 4 + 2] + bb[cb + 2];
                xv.w += acc2[j][hh * 4 + 3] + bb[cb + 3];
                *(float4*)(x + (size_t)r * H + cb) = xv;
            }
        }
    }
}

// ---------------------------------------------------------------------------
__global__ __launch_bounds__(256) void out_head_kernel(
    const float* __restrict__ x, const int* __restrict__ batch,
    const float* __restrict__ w1, const float* __restrict__ b1,
    const float* __restrict__ w2, const float* __restrict__ b2,
    float* __restrict__ energy, int Nn)
{
    __shared__ float As[64][33];
    __shared__ float Ws[32][68];
    __shared__ float e_lds[64];
    __shared__ int   gid_lds[64];

    const int tid = threadIdx.x;
    const int m0 = blockIdx.x * 64;
    const int r0 = (tid >> 4) * 4;
    const int c0 = (tid & 15) * 4;

    float acc[4][4];
    #pragma unroll
    for (int j = 0; j < 4; ++j)
        #pragma unroll
        for (int c = 0; c < 4; ++c) acc[j][c] = 0.0f;

    for (int kc = 0; kc < 128; kc += 32) {
        {
            int r = tid >> 3;
            int kk = (tid & 7) * 4;
            #pragma unroll
            for (int p = 0; p < 2; ++p) {
                int row = r + p * 32;
                float4 v = make_float4(0.f, 0.f, 0.f, 0.f);
                if (m0 + row < Nn) v = *(const float4*)(x + (size_t)(m0 + row) * H + kc + kk);
                As[row][kk] = v.x; As[row][kk + 1] = v.y;
                As[row][kk + 2] = v.z; As[row][kk + 3] = v.w;
            }
        }
        {
            int wr = tid >> 4;
            int wc = (tid & 15) * 4;
            #pragma unroll
            for (int p = 0; p < 2; ++p) {
                int row = wr + p * 16;
                *(float4*)&Ws[row][wc] = *(const float4*)(w1 + (size_t)(kc + row) * 64 + wc);
            }
        }
        __syncthreads();
        #pragma unroll
        for (int k = 0; k < 32; ++k) {
            float a_[4];
            #pragma unroll
            for (int j = 0; j < 4; ++j) a_[j] = As[r0 + j][k];
            float4 wv = *(float4*)&Ws[k][c0];
            float w_[4] = {wv.x, wv.y, wv.z, wv.w};
            #pragma unroll
            for (int j = 0; j < 4; ++j)
                #pragma unroll
                for (int c = 0; c < 4; ++c)
                    acc[j][c] = fmaf(a_[j], w_[c], acc[j][c]);
        }
        __syncthreads();
    }

    const float4 b1v = *(const float4*)(b1 + c0);
    const float4 w2v = *(const float4*)(w2 + c0);
    float ep[4];
    #pragma unroll
    for (int j = 0; j < 4; ++j) {
        float v0 = tanhf(acc[j][0] + b1v.x);
        float v1 = tanhf(acc[j][1] + b1v.y);
        float v2 = tanhf(acc[j][2] + b1v.z);
        float v3 = tanhf(acc[j][3] + b1v.w);
        ep[j] = v0 * w2v.x + v1 * w2v.y + v2 * w2v.z + v3 * w2v.w;
    }
    #pragma unroll
    for (int off = 1; off < 16; off <<= 1) {
        #pragma unroll
        for (int j = 0; j < 4; ++j) ep[j] += __shfl_xor(ep[j], off, 64);
    }
    if ((tid & 15) == 0) {
        const float b2v = b2[0];
        #pragma unroll
        for (int j = 0; j < 4; ++j) e_lds[r0 + j] = ep[j] + b2v;
    }
    if (tid < 64) {
        int row = m0 + tid;
        gid_lds[tid] = (row < Nn) ? batch[row] : -1;
    }
    __syncthreads();

    if (tid == 0) {
        int cur = -1; float sum = 0.0f;
        for (int r = 0; r < 64; ++r) {
            int g = gid_lds[r];
            if (g < 0) continue;
            if (g != cur) {
                if (cur >= 0) atomicAdd(&energy[cur], sum);
                cur = g; sum = 0.0f;
            }
            sum += e_lds[r];
        }
        if (cur >= 0) atomicAdd(&energy[cur], sum);
    }
}

// ---------------------------------------------------------------------------
extern "C" void kernel_launch(void* const* d_in, const int* in_sizes, int n_in,
                              void* d_out, int out_size, void* d_ws, size_t ws_size,
                              hipStream_t stream)
{
    const int*   atype = (const int*)  d_in[0];
    const float* pos   = (const float*)d_in[1];
    const int*   ei    = (const int*)  d_in[2];
    const int*   batch = (const int*)  d_in[3];
    const float* emb   = (const float*)d_in[4];
    const float* fw1   = (const float*)d_in[5];
    const float* fb1   = (const float*)d_in[6];
    const float* fw2   = (const float*)d_in[7];
    const float* fb2   = (const float*)d_in[8];
    const float* lin1w = (const float*)d_in[9];
    const float* lin2w = (const float*)d_in[10];
    const float* lin2b = (const float*)d_in[11];
    const float* blkw  = (const float*)d_in[12];
    const float* blkb  = (const float*)d_in[13];
    const float* ow1   = (const float*)d_in[14];
    const float* ob1   = (const float*)d_in[15];
    const float* ow2   = (const float*)d_in[16];
    const float* ob2   = (const float*)d_in[17];

    const int Nn = in_sizes[0];
    const int E  = in_sizes[2] / 2;
    float* energy = (float*)d_out;

    // workspace layout: cnt + flags contiguous -> single memset
    char* w = (char*)d_ws;
    int*   cnt  = (int*)w;                              // [0]=edges [1]=src [2]=dst [3]=nondst
    int*   is_src = (int*)(w + 256);                    // N
    int*   is_dst = is_src + Nn;                        // N
    float* x    = (float*)(is_dst + Nn);                // N*H
    float* hbuf = x + (size_t)Nn * H;                   // N*H
    float* agg  = hbuf + (size_t)Nn * H;                // N*H
    int*   asrc = (int*)(agg + (size_t)Nn * H);         // E
    int*   adst = asrc + E;                             // E
    float* ad   = (float*)(adst + E);                   // E
    int*   src_list = (int*)(ad + E);                   // N
    int*   dst_list = src_list + Nn;                    // N
    int*   nondst_list = dst_list + Nn;                 // N
    float* cvec = (float*)(nondst_list + Nn);           // 2*H
    float* tab  = cvec + 2 * H;                         // 2*(QT+1)*H
    float4* pos4 = (float4*)(tab + 2 * (size_t)(QT + 1) * H);  // N

    hipMemsetAsync(cnt, 0, 256 + 2 * (size_t)Nn * sizeof(int), stream);
    hipMemsetAsync(energy, 0, (size_t)out_size * sizeof(float), stream);

    {
        int total = (Nn * H) / 4;
        init_x_kernel<<<(total + 255) / 256, 256, 0, stream>>>(atype, emb, x, Nn);
    }
    pos_pad_kernel<<<(Nn + 255) / 256, 256, 0, stream>>>(pos, pos4, Nn);
    edge_prep_kernel<<<(E + 255) / 256, 256, 0, stream>>>(
        pos4, ei, E, cnt, asrc, adst, ad, is_src, is_dst);
    compact_atoms_kernel<<<(Nn + 255) / 256, 256, 0, stream>>>(
        is_src, is_dst, Nn, cnt, src_list, dst_list, nondst_list);
    {
        int waves = 2 * (QT + 1) + 2;
        filter_table_kernel<<<(waves + 3) / 4, 256, 0, stream>>>(
            fw1, fb1, fw2, fb2, lin2b, blkw, blkb, tab, cvec);
    }

    for (int i = 0; i < 2; ++i) {
        const float* l1w  = lin1w + (size_t)i * H * H;
        const float* l2w  = lin2w + (size_t)i * H * H;
        const float* l2b  = lin2b + (size_t)i * H;
        const float* bw   = blkw + (size_t)i * H * H;
        const float* bb   = blkb + (size_t)i * H;
        const float* tabi = tab + (size_t)i * (QT + 1) * H;

        // h[src] = x[src] @ lin1 ; agg[dst] = 0
        gemm_rows_zero_kernel<<<GB + ZB, 256, 0, stream>>>(
            x, l1w, hbuf, src_list, cnt + 1, agg, dst_list, cnt + 2);
        // per-edge: lerp filter table, gather h, scatter agg
        edge_scatter_kernel<<<1024, 256, 0, stream>>>(cnt, asrc, adst, ad,
                                                      tabi, hbuf, agg);
        // x[dst] += tanh(agg@l2w+l2b)@bw + bb ; x[nondst] += cvec_i
        update_x_kernel<<<UB + AB, 256, 0, stream>>>(
            agg, l2w, l2b, bw, bb, x, dst_list, cnt + 2,
            nondst_list, cnt + 3, cvec + i * H);
    }

    out_head_kernel<<<(Nn + 63) / 64, 256, 0, stream>>>(x, batch, ow1, ob1, ow2, ob2, energy, Nn);
}

// Round 7
// 329.967 us; speedup vs baseline: 1.0784x; 1.0784x over previous
//
#include <hip/hip_runtime.h>
#include <hip/hip_bf16.h>
#include <math.h>

#define H 128
#define RBF 50
#define CUTF 5.0f
#define PIF 3.14159265358979323846f
#define QT 1024                       // filter table intervals (QT+1 knots)
#define SEG 16                        // edge-compaction segments (spread counters)

// ---------------------------------------------------------------------------
// Role-split: blocks [0,XB): x[n]=emb[atype[n]]; blocks [XB,..): pos4 pad.
__global__ __launch_bounds__(256) void init_pos_x_kernel(
    const int* __restrict__ atype, const float* __restrict__ emb,
    const float* __restrict__ pos,
    float* __restrict__ x, float4* __restrict__ pos4, int Nn, int XB)
{
    if ((int)blockIdx.x < XB) {
        int idx = blockIdx.x * 256 + threadIdx.x;
        if (idx * 4 >= Nn * H) return;
        int n = idx >> 5;
        int c = (idx & 31) * 4;
        const float4 v = *(const float4*)(emb + atype[n] * H + c);
        *(float4*)(x + n * H + c) = v;
    } else {
        int n = ((int)blockIdx.x - XB) * 256 + threadIdx.x;
        if (n < Nn)
            pos4[n] = make_float4(pos[3 * n], pos[3 * n + 1], pos[3 * n + 2], 0.0f);
    }
}

// ---------------------------------------------------------------------------
// Edge compaction, 4 edges/thread, block-aggregated atomic into 16 spread
// segment counters. Active edges land at seg*CAP + intra-segment offset.
__global__ __launch_bounds__(256) void edge_prep_kernel(
    const float4* __restrict__ pos4, const int* __restrict__ ei, int E, int CAP,
    int* __restrict__ seg_cnt, int* __restrict__ asrc, int* __restrict__ adst,
    float* __restrict__ ad, int* __restrict__ is_src, int* __restrict__ is_dst)
{
    __shared__ int wtot[4], wbase[4];
    const int tid = threadIdx.x;
    const int lane = tid & 63;
    const int wv = tid >> 6;
    const int gtid = blockIdx.x * 256 + tid;

    int s[4], t[4];
    float d[4];
    bool act[4] = {false, false, false, false};

    const int e0 = gtid * 4;
    if (e0 + 3 < E && (E & 3) == 0) {
        const int4 sv = *(const int4*)(ei + e0);
        const int4 tv = *(const int4*)(ei + E + e0);
        s[0] = sv.x; s[1] = sv.y; s[2] = sv.z; s[3] = sv.w;
        t[0] = tv.x; t[1] = tv.y; t[2] = tv.z; t[3] = tv.w;
        #pragma unroll
        for (int j = 0; j < 4; ++j) {
            float4 ps = pos4[s[j]], pt = pos4[t[j]];
            float dx = ps.x - pt.x, dy = ps.y - pt.y, dz = ps.z - pt.z;
            d[j] = sqrtf(dx * dx + dy * dy + dz * dz + 1e-12f);
            act[j] = (d[j] < CUTF);
        }
    } else if (e0 < E) {
        #pragma unroll
        for (int j = 0; j < 4; ++j) {
            int e = e0 + j;
            if (e < E) {
                s[j] = ei[e]; t[j] = ei[E + e];
                float4 ps = pos4[s[j]], pt = pos4[t[j]];
                float dx = ps.x - pt.x, dy = ps.y - pt.y, dz = ps.z - pt.z;
                d[j] = sqrtf(dx * dx + dy * dy + dz * dz + 1e-12f);
                act[j] = (d[j] < CUTF);
            }
        }
    }

    unsigned long long b[4];
    int mytot = 0;
    #pragma unroll
    for (int j = 0; j < 4; ++j) {
        b[j] = __ballot(act[j]);
        mytot += (int)__popcll(b[j]);
    }
    if (lane == 0) wtot[wv] = mytot;
    __syncthreads();
    if (tid == 0) {
        int t0 = wtot[0], t1 = wtot[1], t2 = wtot[2], t3 = wtot[3];
        int tot = t0 + t1 + t2 + t3;
        int base = 0;
        if (tot) base = atomicAdd(&seg_cnt[blockIdx.x & (SEG - 1)], tot);
        wbase[0] = base; wbase[1] = base + t0;
        wbase[2] = base + t0 + t1; wbase[3] = base + t0 + t1 + t2;
    }
    __syncthreads();

    int run = wbase[wv];
    const int segoff = (int)(blockIdx.x & (SEG - 1)) * CAP;
    const unsigned long long ltm = ((unsigned long long)1 << lane) - 1;
    #pragma unroll
    for (int j = 0; j < 4; ++j) {
        if (act[j]) {
            int p = segoff + run + (int)__popcll(b[j] & ltm);
            asrc[p] = s[j]; adst[p] = t[j]; ad[p] = d[j];
            is_src[s[j]] = 1; is_dst[t[j]] = 1;
        }
        run += (int)__popcll(b[j]);
    }
}

// ---------------------------------------------------------------------------
// Atom list compaction, block-aggregated (one atomic per list per block).
__global__ __launch_bounds__(256) void compact_atoms_kernel(
    const int* __restrict__ is_src, const int* __restrict__ is_dst, int Nn,
    int* __restrict__ cnt4,
    int* __restrict__ src_list, int* __restrict__ dst_list, int* __restrict__ nondst_list)
{
    __shared__ int wtot[3][4], wbase[3][4];
    const int tid = threadIdx.x;
    const int lane = tid & 63;
    const int wv = tid >> 6;
    int n = blockIdx.x * 256 + tid;
    bool v[3] = {false, false, false};
    if (n < Nn) {
        v[0] = is_src[n] != 0;
        v[1] = is_dst[n] != 0;
        v[2] = !v[1];
    }
    unsigned long long b[3];
    #pragma unroll
    for (int l = 0; l < 3; ++l) {
        b[l] = __ballot(v[l]);
        if (lane == 0) wtot[l][wv] = (int)__popcll(b[l]);
    }
    __syncthreads();
    if (tid == 0) {
        #pragma unroll
        for (int l = 0; l < 3; ++l) {
            int t0 = wtot[l][0], t1 = wtot[l][1], t2 = wtot[l][2], t3 = wtot[l][3];
            int tot = t0 + t1 + t2 + t3;
            int base = 0;
            if (tot) base = atomicAdd(cnt4 + 1 + l, tot);
            wbase[l][0] = base; wbase[l][1] = base + t0;
            wbase[l][2] = base + t0 + t1; wbase[l][3] = base + t0 + t1 + t2;
        }
    }
    __syncthreads();
    const unsigned long long ltm = ((unsigned long long)1 << lane) - 1;
    if (v[0]) src_list[wbase[0][wv] + (int)__popcll(b[0] & ltm)] = n;
    if (v[1]) dst_list[wbase[1][wv] + (int)__popcll(b[1] & ltm)] = n;
    if (v[2]) nondst_list[wbase[2][wv] + (int)__popcll(b[2] & ltm)] = n;
}

// ---------------------------------------------------------------------------
// Filter table + cvec, one wave per task.
__global__ __launch_bounds__(256) void filter_table_kernel(
    const float* __restrict__ fw1, const float* __restrict__ fb1,
    const float* __restrict__ fw2, const float* __restrict__ fb2,
    const float* __restrict__ lin2b, const float* __restrict__ blkw,
    const float* __restrict__ blkb,
    float* __restrict__ tab, float* __restrict__ cvec)
{
    const int lane = threadIdx.x & 63;
    const int wid = (blockIdx.x * blockDim.x + threadIdx.x) >> 6;
    const int ntab = 2 * (QT + 1);
    if (wid >= ntab + 2) return;
    const int h0 = lane, h1 = lane + 64;

    if (wid >= ntab) {
        const int blk = wid - ntab;
        const float* bwp = blkw + (size_t)blk * H * H;
        float t0 = tanhf(lin2b[blk * H + h0]);
        float t1 = tanhf(lin2b[blk * H + h1]);
        float a0 = blkb[blk * H + h0], a1 = blkb[blk * H + h1];
        #pragma unroll 8
        for (int k = 0; k < 64; ++k) {
            float bb = __shfl(t0, k, 64);
            a0 = fmaf(bb, bwp[k * H + h0], a0);
            a1 = fmaf(bb, bwp[k * H + h1], a1);
        }
        #pragma unroll 8
        for (int k = 0; k < 64; ++k) {
            float bb = __shfl(t1, k, 64);
            a0 = fmaf(bb, bwp[(64 + k) * H + h0], a0);
            a1 = fmaf(bb, bwp[(64 + k) * H + h1], a1);
        }
        cvec[blk * H + h0] = a0;
        cvec[blk * H + h1] = a1;
        return;
    }

    const int blk = wid / (QT + 1);
    const int q = wid - blk * (QT + 1);
    const float d = (float)q * (CUTF / (float)QT);

    const float* f1 = fw1 + (size_t)blk * RBF * H;
    const float* f2 = fw2 + (size_t)blk * H * H;
    const float step  = CUTF / 49.0f;
    const float coeff = -0.5f / (step * step);

    float cenv = (d < CUTF) ? 0.5f * (cosf(d * (PIF / CUTF)) + 1.0f) : 0.0f;

    float t0 = fb1[blk * H + h0], t1 = fb1[blk * H + h1];
    #pragma unroll
    for (int r = 0; r < RBF; ++r) {
        float u = d - (float)r * step;
        float rb = expf(coeff * u * u);
        t0 = fmaf(rb, f1[r * H + h0], t0);
        t1 = fmaf(rb, f1[r * H + h1], t1);
    }
    t0 = tanhf(t0); t1 = tanhf(t1);

    float w0 = fb2[blk * H + h0], w1v = fb2[blk * H + h1];
    #pragma unroll 8
    for (int k = 0; k < 64; ++k) {
        float bb = __shfl(t0, k, 64);
        w0  = fmaf(bb, f2[k * H + h0], w0);
        w1v = fmaf(bb, f2[k * H + h1], w1v);
    }
    #pragma unroll 8
    for (int k = 0; k < 64; ++k) {
        float bb = __shfl(t1, k, 64);
        w0  = fmaf(bb, f2[(64 + k) * H + h0], w0);
        w1v = fmaf(bb, f2[(64 + k) * H + h1], w1v);
    }
    float* row = tab + ((size_t)blk * (QT + 1) + q) * H;
    row[h0] = w0 * cenv;
    row[h1] = w1v * cenv;
}

// ---------------------------------------------------------------------------
// Per-edge scatter over segmented edge arrays.
__global__ __launch_bounds__(256) void edge_scatter_kernel(
    const int* __restrict__ seg_cnt,
    const int* __restrict__ asrc, const int* __restrict__ adst,
    const float* __restrict__ ad, const float* __restrict__ tab,
    const float* __restrict__ hbuf, float* __restrict__ agg, int CAP)
{
    const int lane = threadIdx.x & 63;
    const int wid = (blockIdx.x * blockDim.x + threadIdx.x) >> 6;
    const int nw  = (gridDim.x * blockDim.x) >> 6;
    const int total_slots = SEG * CAP;
    const float scale = (float)QT / CUTF;

    for (int slot = wid; slot < total_slots; slot += nw) {
        int seg = slot / CAP;
        int idx = slot - seg * CAP;
        if (idx >= seg_cnt[seg]) continue;    // one cache line holds all 16 counts
        int s = asrc[slot], t = adst[slot];
        float p = ad[slot] * scale;
        int i0 = (int)p;
        if (i0 > QT - 1) i0 = QT - 1;
        float f = p - (float)i0;
        const float* r0 = tab + (size_t)i0 * H;
        float wl = fmaf(f, r0[H + lane] - r0[lane], r0[lane]);
        float wh = fmaf(f, r0[H + 64 + lane] - r0[64 + lane], r0[64 + lane]);
        float m0 = hbuf[(size_t)s * H + lane] * wl;
        float m1 = hbuf[(size_t)s * H + 64 + lane] * wh;
        atomicAdd(agg + (size_t)t * H + lane, m0);
        atomicAdd(agg + (size_t)t * H + 64 + lane, m1);
    }
}

// ---------------------------------------------------------------------------
// Role-split: blocks [0,GB): gathered GEMM; [GB,GB+ZB): zero agg rows.
#define GB 512
#define ZB 128
__global__ __launch_bounds__(256) void gemm_rows_zero_kernel(
    const float* __restrict__ A, const float* __restrict__ W,
    float* __restrict__ C,
    const int* __restrict__ rows, const int* __restrict__ cntp,
    float* __restrict__ zbuf, const int* __restrict__ zrows,
    const int* __restrict__ zcntp)
{
    __shared__ float As[32][36];
    __shared__ float Ws[32][128];
    __shared__ int rlist[32];

    const int tid = threadIdx.x;

    if (blockIdx.x >= GB) {
        int zcnt = *zcntp;
        int total = zcnt * 32;
        for (int idx = (blockIdx.x - GB) * 256 + tid; idx < total; idx += ZB * 256) {
            int row = idx >> 5, c = (idx & 31) << 2;
            int r = zrows[row];
            *(float4*)(zbuf + (size_t)r * H + c) = make_float4(0.f, 0.f, 0.f, 0.f);
        }
        return;
    }

    const int cnt = *cntp;
    const int r0 = (tid >> 4) * 2;
    const int c0 = (tid & 15) * 4;

    for (int tile = blockIdx.x; tile * 32 < cnt; tile += GB) {
        __syncthreads();
        if (tid < 32) {
            int idx = tile * 32 + tid;
            rlist[tid] = (idx < cnt) ? rows[idx] : -1;
        }
        __syncthreads();

        float acc[2][8];
        #pragma unroll
        for (int j = 0; j < 2; ++j)
            #pragma unroll
            for (int c = 0; c < 8; ++c) acc[j][c] = 0.f;

        for (int kc = 0; kc < H; kc += 32) {
            {
                int lr = tid >> 3;
                int kk = (tid & 7) * 4;
                int r = rlist[lr];
                float4 v = make_float4(0.f, 0.f, 0.f, 0.f);
                if (r >= 0) v = *(const float4*)(A + (size_t)r * H + kc + kk);
                *(float4*)&As[lr][kk] = v;
            }
            {
                int wr = tid >> 5;
                int wc = (tid & 31) * 4;
                #pragma unroll
                for (int p = 0; p < 4; ++p) {
                    int row = wr + p * 8;
                    *(float4*)&Ws[row][wc] = *(const float4*)(W + (size_t)(kc + row) * H + wc);
                }
            }
            __syncthreads();
            #pragma unroll
            for (int k = 0; k < 32; k += 4) {
                float a_[2][4];
                #pragma unroll
                for (int j = 0; j < 2; ++j)
                    *(float4*)a_[j] = *(const float4*)&As[r0 + j][k];
                #pragma unroll
                for (int kk = 0; kk < 4; ++kk) {
                    float4 wlo = *(const float4*)&Ws[k + kk][c0];
                    float4 whi = *(const float4*)&Ws[k + kk][c0 + 64];
                    float w_[8] = {wlo.x, wlo.y, wlo.z, wlo.w, whi.x, whi.y, whi.z, whi.w};
                    #pragma unroll
                    for (int j = 0; j < 2; ++j)
                        #pragma unroll
                        for (int c = 0; c < 8; ++c)
                            acc[j][c] = fmaf(a_[j][kk], w_[c], acc[j][c]);
                }
            }
            __syncthreads();
        }
        #pragma unroll
        for (int j = 0; j < 2; ++j) {
            int r = rlist[r0 + j];
            if (r < 0) continue;
            #pragma unroll
            for (int hh = 0; hh < 2; ++hh) {
                int cb = c0 + hh * 64;
                *(float4*)(C + (size_t)r * H + cb) = make_float4(
                    acc[j][hh * 4 + 0], acc[j][hh * 4 + 1],
                    acc[j][hh * 4 + 2], acc[j][hh * 4 + 3]);
            }
        }
    }
}

// ---------------------------------------------------------------------------
// Role-split x update: [0,UB) dst GEMM path; [UB,UB+AB) nondst cvec add.
#define UB 512
#define AB 256
__global__ __launch_bounds__(256) void update_x_kernel(
    const float* __restrict__ agg, const float* __restrict__ l2w,
    const float* __restrict__ l2b, const float* __restrict__ bw,
    const float* __restrict__ bb, float* __restrict__ x,
    const int* __restrict__ rows, const int* __restrict__ cntp,
    const int* __restrict__ nrows, const int* __restrict__ ncntp,
    const float* __restrict__ cvec)
{
    __shared__ float As[32][36];
    __shared__ float Ws[32][128];
    __shared__ float Tl[32][132];
    __shared__ int rlist[32];

    const int tid = threadIdx.x;

    if (blockIdx.x >= UB) {
        int ncnt = *ncntp;
        int total = ncnt * 32;
        for (int idx = (blockIdx.x - UB) * 256 + tid; idx < total; idx += AB * 256) {
            int row = idx >> 5, c = (idx & 31) << 2;
            int r = nrows[row];
            float4 v = *(const float4*)(x + (size_t)r * H + c);
            float4 cv = *(const float4*)(cvec + c);
            v.x += cv.x; v.y += cv.y; v.z += cv.z; v.w += cv.w;
            *(float4*)(x + (size_t)r * H + c) = v;
        }
        return;
    }

    const int cnt = *cntp;
    const int r0 = (tid >> 4) * 2;
    const int c0 = (tid & 15) * 4;

    for (int tile = blockIdx.x; tile * 32 < cnt; tile += UB) {
        __syncthreads();
        if (tid < 32) {
            int idx = tile * 32 + tid;
            rlist[tid] = (idx < cnt) ? rows[idx] : -1;
        }
        __syncthreads();

        float acc[2][8];
        #pragma unroll
        for (int j = 0; j < 2; ++j)
            #pragma unroll
            for (int c = 0; c < 8; ++c) acc[j][c] = 0.f;

        for (int kc = 0; kc < H; kc += 32) {
            {
                int lr = tid >> 3;
                int kk = (tid & 7) * 4;
                int r = rlist[lr];
                float4 v = make_float4(0.f, 0.f, 0.f, 0.f);
                if (r >= 0) v = *(const float4*)(agg + (size_t)r * H + kc + kk);
                *(float4*)&As[lr][kk] = v;
            }
            {
                int wr = tid >> 5;
                int wc = (tid & 31) * 4;
                #pragma unroll
                for (int p = 0; p < 4; ++p) {
                    int row = wr + p * 8;
                    *(float4*)&Ws[row][wc] = *(const float4*)(l2w + (size_t)(kc + row) * H + wc);
                }
            }
            __syncthreads();
            #pragma unroll
            for (int k = 0; k < 32; k += 4) {
                float a_[2][4];
                #pragma unroll
                for (int j = 0; j < 2; ++j)
                    *(float4*)a_[j] = *(const float4*)&As[r0 + j][k];
                #pragma unroll
                for (int kk = 0; kk < 4; ++kk) {
                    float4 wlo = *(const float4*)&Ws[k + kk][c0];
                    float4 whi = *(const float4*)&Ws[k + kk][c0 + 64];
                    float w_[8] = {wlo.x, wlo.y, wlo.z, wlo.w, whi.x, whi.y, whi.z, whi.w};
                    #pragma unroll
                    for (int j = 0; j < 2; ++j)
                        #pragma unroll
                        for (int c = 0; c < 8; ++c)
                            acc[j][c] = fmaf(a_[j][kk], w_[c], acc[j][c]);
                }
            }
            __syncthreads();
        }
        #pragma unroll
        for (int j = 0; j < 2; ++j) {
            float4 lo, hi;
            lo.x = tanhf(acc[j][0] + l2b[c0]);      lo.y = tanhf(acc[j][1] + l2b[c0 + 1]);
            lo.z = tanhf(acc[j][2] + l2b[c0 + 2]);  lo.w = tanhf(acc[j][3] + l2b[c0 + 3]);
            hi.x = tanhf(acc[j][4] + l2b[c0 + 64]); hi.y = tanhf(acc[j][5] + l2b[c0 + 65]);
            hi.z = tanhf(acc[j][6] + l2b[c0 + 66]); hi.w = tanhf(acc[j][7] + l2b[c0 + 67]);
            *(float4*)&Tl[r0 + j][c0] = lo;
            *(float4*)&Tl[r0 + j][c0 + 64] = hi;
        }

        float acc2[2][8];
        #pragma unroll
        for (int j = 0; j < 2; ++j)
            #pragma unroll
            for (int c = 0; c < 8; ++c) acc2[j][c] = 0.f;

        for (int kc = 0; kc < H; kc += 32) {
            __syncthreads();
            {
                int wr = tid >> 5;
                int wc = (tid & 31) * 4;
                #pragma unroll
                for (int p = 0; p < 4; ++p) {
                    int row = wr + p * 8;
                    *(float4*)&Ws[row][wc] = *(const float4*)(bw + (size_t)(kc + row) * H + wc);
                }
            }
            __syncthreads();
            #pragma unroll
            for (int k = 0; k < 32; k += 4) {
                float a_[2][4];
                #pragma unroll
                for (int j = 0; j < 2; ++j)
                    *(float4*)a_[j] = *(const float4*)&Tl[r0 + j][kc + k];
                #pragma unroll
                for (int kk = 0; kk < 4; ++kk) {
                    float4 wlo = *(const float4*)&Ws[k + kk][c0];
                    float4 whi = *(const float4*)&Ws[k + kk][c0 + 64];
                    float w_[8] = {wlo.x, wlo.y, wlo.z, wlo.w, whi.x, whi.y, whi.z, whi.w};
                    #pragma unroll
                    for (int j = 0; j < 2; ++j)
                        #pragma unroll
                        for (int c = 0; c < 8; ++c)
                            acc2[j][c] = fmaf(a_[j][kk], w_[c], acc2[j][c]);
                }
            }
        }
        #pragma unroll
        for (int j = 0; j < 2; ++j) {
            int r = rlist[r0 + j];
            if (r < 0) continue;
            #pragma unroll
            for (int hh = 0; hh < 2; ++hh) {
                int cb = c0 + hh * 64;
                float4 xv = *(const float4*)(x + (size_t)r * H + cb);
                xv.x += acc2[j][hh * 4 + 0] + bb[cb];
                xv.y += acc2[j][hh * 4 + 1] + bb[cb + 1];
                xv.z += acc2[j][hh * 4 + 2] + bb[cb + 2];
                xv.w += acc2[j][hh * 4 + 3] + bb[cb + 3];
                *(float4*)(x + (size_t)r * H + cb) = xv;
            }
        }
    }
}

// ---------------------------------------------------------------------------
__global__ __launch_bounds__(256) void out_head_kernel(
    const float* __restrict__ x, const int* __restrict__ batch,
    const float* __restrict__ w1, const float* __restrict__ b1,
    const float* __restrict__ w2, const float* __restrict__ b2,
    float* __restrict__ energy, int Nn)
{
    __shared__ float As[64][33];
    __shared__ float Ws[32][68];
    __shared__ float e_lds[64];
    __shared__ int   gid_lds[64];

    const int tid = threadIdx.x;
    const int m0 = blockIdx.x * 64;
    const int r0 = (tid >> 4) * 4;
    const int c0 = (tid & 15) * 4;

    float acc[4][4];
    #pragma unroll
    for (int j = 0; j < 4; ++j)
        #pragma unroll
        for (int c = 0; c < 4; ++c) acc[j][c] = 0.0f;

    for (int kc = 0; kc < 128; kc += 32) {
        {
            int r = tid >> 3;
            int kk = (tid & 7) * 4;
            #pragma unroll
            for (int p = 0; p < 2; ++p) {
                int row = r + p * 32;
                float4 v = make_float4(0.f, 0.f, 0.f, 0.f);
                if (m0 + row < Nn) v = *(const float4*)(x + (size_t)(m0 + row) * H + kc + kk);
                As[row][kk] = v.x; As[row][kk + 1] = v.y;
                As[row][kk + 2] = v.z; As[row][kk + 3] = v.w;
            }
        }
        {
            int wr = tid >> 4;
            int wc = (tid & 15) * 4;
            #pragma unroll
            for (int p = 0; p < 2; ++p) {
                int row = wr + p * 16;
                *(float4*)&Ws[row][wc] = *(const float4*)(w1 + (size_t)(kc + row) * 64 + wc);
            }
        }
        __syncthreads();
        #pragma unroll
        for (int k = 0; k < 32; ++k) {
            float a_[4];
            #pragma unroll
            for (int j = 0; j < 4; ++j) a_[j] = As[r0 + j][k];
            float4 wv = *(float4*)&Ws[k][c0];
            float w_[4] = {wv.x, wv.y, wv.z, wv.w};
            #pragma unroll
            for (int j = 0; j < 4; ++j)
                #pragma unroll
                for (int c = 0; c < 4; ++c)
                    acc[j][c] = fmaf(a_[j], w_[c], acc[j][c]);
        }
        __syncthreads();
    }

    const float4 b1v = *(const float4*)(b1 + c0);
    const float4 w2v = *(const float4*)(w2 + c0);
    float ep[4];
    #pragma unroll
    for (int j = 0; j < 4; ++j) {
        float v0 = tanhf(acc[j][0] + b1v.x);
        float v1 = tanhf(acc[j][1] + b1v.y);
        float v2 = tanhf(acc[j][2] + b1v.z);
        float v3 = tanhf(acc[j][3] + b1v.w);
        ep[j] = v0 * w2v.x + v1 * w2v.y + v2 * w2v.z + v3 * w2v.w;
    }
    #pragma unroll
    for (int off = 1; off < 16; off <<= 1) {
        #pragma unroll
        for (int j = 0; j < 4; ++j) ep[j] += __shfl_xor(ep[j], off, 64);
    }
    if ((tid & 15) == 0) {
        const float b2v = b2[0];
        #pragma unroll
        for (int j = 0; j < 4; ++j) e_lds[r0 + j] = ep[j] + b2v;
    }
    if (tid < 64) {
        int row = m0 + tid;
        gid_lds[tid] = (row < Nn) ? batch[row] : -1;
    }
    __syncthreads();

    if (tid == 0) {
        int cur = -1; float sum = 0.0f;
        for (int r = 0; r < 64; ++r) {
            int g = gid_lds[r];
            if (g < 0) continue;
            if (g != cur) {
                if (cur >= 0) atomicAdd(&energy[cur], sum);
                cur = g; sum = 0.0f;
            }
            sum += e_lds[r];
        }
        if (cur >= 0) atomicAdd(&energy[cur], sum);
    }
}

// ---------------------------------------------------------------------------
extern "C" void kernel_launch(void* const* d_in, const int* in_sizes, int n_in,
                              void* d_out, int out_size, void* d_ws, size_t ws_size,
                              hipStream_t stream)
{
    const int*   atype = (const int*)  d_in[0];
    const float* pos   = (const float*)d_in[1];
    const int*   ei    = (const int*)  d_in[2];
    const int*   batch = (const int*)  d_in[3];
    const float* emb   = (const float*)d_in[4];
    const float* fw1   = (const float*)d_in[5];
    const float* fb1   = (const float*)d_in[6];
    const float* fw2   = (const float*)d_in[7];
    const float* fb2   = (const float*)d_in[8];
    const float* lin1w = (const float*)d_in[9];
    const float* lin2w = (const float*)d_in[10];
    const float* lin2b = (const float*)d_in[11];
    const float* blkw  = (const float*)d_in[12];
    const float* blkb  = (const float*)d_in[13];
    const float* ow1   = (const float*)d_in[14];
    const float* ob1   = (const float*)d_in[15];
    const float* ow2   = (const float*)d_in[16];
    const float* ob2   = (const float*)d_in[17];

    const int Nn = in_sizes[0];
    const int E  = in_sizes[2] / 2;
    float* energy = (float*)d_out;

    // edge segmentation geometry
    const int eblocks = (E + 1023) / 1024;                // 4 edges/thread, 256 thr
    const int bps = (eblocks + SEG - 1) / SEG;
    const int CAP = bps * 1024;                           // per-segment capacity
    const int SEGCAP = SEG * CAP;

    // workspace layout: cnt/seg_cnt + flags contiguous -> single memset
    char* w = (char*)d_ws;
    int*   cnt  = (int*)w;           // [1]=src [2]=dst [3]=nondst ; [8..23]=seg_cnt
    int*   seg_cnt = cnt + 8;
    int*   is_src = (int*)(w + 256);                    // N
    int*   is_dst = is_src + Nn;                        // N
    float* x    = (float*)(is_dst + Nn);                // N*H
    float* hbuf = x + (size_t)Nn * H;                   // N*H
    float* agg  = hbuf + (size_t)Nn * H;                // N*H
    int*   asrc = (int*)(agg + (size_t)Nn * H);         // SEGCAP
    int*   adst = asrc + SEGCAP;                        // SEGCAP
    float* ad   = (float*)(adst + SEGCAP);              // SEGCAP
    int*   src_list = (int*)(ad + SEGCAP);              // N
    int*   dst_list = src_list + Nn;                    // N
    int*   nondst_list = dst_list + Nn;                 // N
    float* cvec = (float*)(nondst_list + Nn);           // 2*H
    float* tab  = cvec + 2 * H;                         // 2*(QT+1)*H
    float4* pos4 = (float4*)(tab + 2 * (size_t)(QT + 1) * H);  // N

    hipMemsetAsync(cnt, 0, 256 + 2 * (size_t)Nn * sizeof(int), stream);
    hipMemsetAsync(energy, 0, (size_t)out_size * sizeof(float), stream);

    {
        int XB = (Nn * 32 + 255) / 256;
        int PB = (Nn + 255) / 256;
        init_pos_x_kernel<<<XB + PB, 256, 0, stream>>>(atype, emb, pos, x, pos4, Nn, XB);
    }
    edge_prep_kernel<<<eblocks, 256, 0, stream>>>(
        pos4, ei, E, CAP, seg_cnt, asrc, adst, ad, is_src, is_dst);
    compact_atoms_kernel<<<(Nn + 255) / 256, 256, 0, stream>>>(
        is_src, is_dst, Nn, cnt, src_list, dst_list, nondst_list);
    {
        int waves = 2 * (QT + 1) + 2;
        filter_table_kernel<<<(waves + 3) / 4, 256, 0, stream>>>(
            fw1, fb1, fw2, fb2, lin2b, blkw, blkb, tab, cvec);
    }

    for (int i = 0; i < 2; ++i) {
        const float* l1w  = lin1w + (size_t)i * H * H;
        const float* l2w  = lin2w + (size_t)i * H * H;
        const float* l2b  = lin2b + (size_t)i * H;
        const float* bw   = blkw + (size_t)i * H * H;
        const float* bb   = blkb + (size_t)i * H;
        const float* tabi = tab + (size_t)i * (QT + 1) * H;

        gemm_rows_zero_kernel<<<GB + ZB, 256, 0, stream>>>(
            x, l1w, hbuf, src_list, cnt + 1, agg, dst_list, cnt + 2);
        edge_scatter_kernel<<<1024, 256, 0, stream>>>(seg_cnt, asrc, adst, ad,
                                                      tabi, hbuf, agg, CAP);
        update_x_kernel<<<UB + AB, 256, 0, stream>>>(
            agg, l2w, l2b, bw, bb, x, dst_list, cnt + 2,
            nondst_list, cnt + 3, cvec + i * H);
    }

    out_head_kernel<<<(Nn + 63) / 64, 256, 0, stream>>>(x, batch, ow1, ob1, ow2, ob2, energy, Nn);
}

// Round 8
// 250.714 us; speedup vs baseline: 1.4193x; 1.3161x over previous
//
#include <hip/hip_runtime.h>
#include <hip/hip_bf16.h>
#include <math.h>

#define H 128
#define RBF 50
#define CUTF 5.0f
#define PIF 3.14159265358979323846f
#define QT 1024                       // filter table intervals (QT+1 knots)
#define SEG 16                        // edge-compaction segments (spread counters)

// ---------------------------------------------------------------------------
// Role-split: blocks [0,XB): x[n]=emb[atype[n]]; blocks [XB,..): pos4 pad.
__global__ __launch_bounds__(256) void init_pos_x_kernel(
    const int* __restrict__ atype, const float* __restrict__ emb,
    const float* __restrict__ pos,
    float* __restrict__ x, float4* __restrict__ pos4, int Nn, int XB)
{
    if ((int)blockIdx.x < XB) {
        int idx = blockIdx.x * 256 + threadIdx.x;
        if (idx * 4 >= Nn * H) return;
        int n = idx >> 5;
        int c = (idx & 31) * 4;
        const float4 v = *(const float4*)(emb + atype[n] * H + c);
        *(float4*)(x + n * H + c) = v;
    } else {
        int n = ((int)blockIdx.x - XB) * 256 + threadIdx.x;
        if (n < Nn)
            pos4[n] = make_float4(pos[3 * n], pos[3 * n + 1], pos[3 * n + 2], 0.0f);
    }
}

// ---------------------------------------------------------------------------
// Edge compaction, 4 edges/thread, block-aggregated atomic into 16 spread
// segment counters. Active edges land at seg*CAP + intra-segment offset.
__global__ __launch_bounds__(256) void edge_prep_kernel(
    const float4* __restrict__ pos4, const int* __restrict__ ei, int E, int CAP,
    int* __restrict__ seg_cnt, int* __restrict__ asrc, int* __restrict__ adst,
    float* __restrict__ ad, int* __restrict__ is_src, int* __restrict__ is_dst)
{
    __shared__ int wtot[4], wbase[4];
    const int tid = threadIdx.x;
    const int lane = tid & 63;
    const int wv = tid >> 6;
    const int gtid = blockIdx.x * 256 + tid;

    int s[4], t[4];
    float d[4];
    bool act[4] = {false, false, false, false};

    const int e0 = gtid * 4;
    if (e0 + 3 < E && (E & 3) == 0) {
        const int4 sv = *(const int4*)(ei + e0);
        const int4 tv = *(const int4*)(ei + E + e0);
        s[0] = sv.x; s[1] = sv.y; s[2] = sv.z; s[3] = sv.w;
        t[0] = tv.x; t[1] = tv.y; t[2] = tv.z; t[3] = tv.w;
        #pragma unroll
        for (int j = 0; j < 4; ++j) {
            float4 ps = pos4[s[j]], pt = pos4[t[j]];
            float dx = ps.x - pt.x, dy = ps.y - pt.y, dz = ps.z - pt.z;
            d[j] = sqrtf(dx * dx + dy * dy + dz * dz + 1e-12f);
            act[j] = (d[j] < CUTF);
        }
    } else if (e0 < E) {
        #pragma unroll
        for (int j = 0; j < 4; ++j) {
            int e = e0 + j;
            if (e < E) {
                s[j] = ei[e]; t[j] = ei[E + e];
                float4 ps = pos4[s[j]], pt = pos4[t[j]];
                float dx = ps.x - pt.x, dy = ps.y - pt.y, dz = ps.z - pt.z;
                d[j] = sqrtf(dx * dx + dy * dy + dz * dz + 1e-12f);
                act[j] = (d[j] < CUTF);
            }
        }
    }

    unsigned long long b[4];
    int mytot = 0;
    #pragma unroll
    for (int j = 0; j < 4; ++j) {
        b[j] = __ballot(act[j]);
        mytot += (int)__popcll(b[j]);
    }
    if (lane == 0) wtot[wv] = mytot;
    __syncthreads();
    if (tid == 0) {
        int t0 = wtot[0], t1 = wtot[1], t2 = wtot[2], t3 = wtot[3];
        int tot = t0 + t1 + t2 + t3;
        int base = 0;
        if (tot) base = atomicAdd(&seg_cnt[blockIdx.x & (SEG - 1)], tot);
        wbase[0] = base; wbase[1] = base + t0;
        wbase[2] = base + t0 + t1; wbase[3] = base + t0 + t1 + t2;
    }
    __syncthreads();

    int run = wbase[wv];
    const int segoff = (int)(blockIdx.x & (SEG - 1)) * CAP;
    const unsigned long long ltm = ((unsigned long long)1 << lane) - 1;
    #pragma unroll
    for (int j = 0; j < 4; ++j) {
        if (act[j]) {
            int p = segoff + run + (int)__popcll(b[j] & ltm);
            asrc[p] = s[j]; adst[p] = t[j]; ad[p] = d[j];
            is_src[s[j]] = 1; is_dst[t[j]] = 1;
        }
        run += (int)__popcll(b[j]);
    }
}

// ---------------------------------------------------------------------------
// Atom list compaction, block-aggregated (one atomic per list per block).
__global__ __launch_bounds__(256) void compact_atoms_kernel(
    const int* __restrict__ is_src, const int* __restrict__ is_dst, int Nn,
    int* __restrict__ cnt4,
    int* __restrict__ src_list, int* __restrict__ dst_list, int* __restrict__ nondst_list)
{
    __shared__ int wtot[3][4], wbase[3][4];
    const int tid = threadIdx.x;
    const int lane = tid & 63;
    const int wv = tid >> 6;
    int n = blockIdx.x * 256 + tid;
    bool v[3] = {false, false, false};
    if (n < Nn) {
        v[0] = is_src[n] != 0;
        v[1] = is_dst[n] != 0;
        v[2] = !v[1];
    }
    unsigned long long b[3];
    #pragma unroll
    for (int l = 0; l < 3; ++l) {
        b[l] = __ballot(v[l]);
        if (lane == 0) wtot[l][wv] = (int)__popcll(b[l]);
    }
    __syncthreads();
    if (tid == 0) {
        #pragma unroll
        for (int l = 0; l < 3; ++l) {
            int t0 = wtot[l][0], t1 = wtot[l][1], t2 = wtot[l][2], t3 = wtot[l][3];
            int tot = t0 + t1 + t2 + t3;
            int base = 0;
            if (tot) base = atomicAdd(cnt4 + 1 + l, tot);
            wbase[l][0] = base; wbase[l][1] = base + t0;
            wbase[l][2] = base + t0 + t1; wbase[l][3] = base + t0 + t1 + t2;
        }
    }
    __syncthreads();
    const unsigned long long ltm = ((unsigned long long)1 << lane) - 1;
    if (v[0]) src_list[wbase[0][wv] + (int)__popcll(b[0] & ltm)] = n;
    if (v[1]) dst_list[wbase[1][wv] + (int)__popcll(b[1] & ltm)] = n;
    if (v[2]) nondst_list[wbase[2][wv] + (int)__popcll(b[2] & ltm)] = n;
}

// ---------------------------------------------------------------------------
// Filter table + cvec, one wave per task.
__global__ __launch_bounds__(256) void filter_table_kernel(
    const float* __restrict__ fw1, const float* __restrict__ fb1,
    const float* __restrict__ fw2, const float* __restrict__ fb2,
    const float* __restrict__ lin2b, const float* __restrict__ blkw,
    const float* __restrict__ blkb,
    float* __restrict__ tab, float* __restrict__ cvec)
{
    const int lane = threadIdx.x & 63;
    const int wid = (blockIdx.x * blockDim.x + threadIdx.x) >> 6;
    const int ntab = 2 * (QT + 1);
    if (wid >= ntab + 2) return;
    const int h0 = lane, h1 = lane + 64;

    if (wid >= ntab) {
        const int blk = wid - ntab;
        const float* bwp = blkw + (size_t)blk * H * H;
        float t0 = tanhf(lin2b[blk * H + h0]);
        float t1 = tanhf(lin2b[blk * H + h1]);
        float a0 = blkb[blk * H + h0], a1 = blkb[blk * H + h1];
        #pragma unroll 8
        for (int k = 0; k < 64; ++k) {
            float bb = __shfl(t0, k, 64);
            a0 = fmaf(bb, bwp[k * H + h0], a0);
            a1 = fmaf(bb, bwp[k * H + h1], a1);
        }
        #pragma unroll 8
        for (int k = 0; k < 64; ++k) {
            float bb = __shfl(t1, k, 64);
            a0 = fmaf(bb, bwp[(64 + k) * H + h0], a0);
            a1 = fmaf(bb, bwp[(64 + k) * H + h1], a1);
        }
        cvec[blk * H + h0] = a0;
        cvec[blk * H + h1] = a1;
        return;
    }

    const int blk = wid / (QT + 1);
    const int q = wid - blk * (QT + 1);
    const float d = (float)q * (CUTF / (float)QT);

    const float* f1 = fw1 + (size_t)blk * RBF * H;
    const float* f2 = fw2 + (size_t)blk * H * H;
    const float step  = CUTF / 49.0f;
    const float coeff = -0.5f / (step * step);

    float cenv = (d < CUTF) ? 0.5f * (cosf(d * (PIF / CUTF)) + 1.0f) : 0.0f;

    float t0 = fb1[blk * H + h0], t1 = fb1[blk * H + h1];
    #pragma unroll
    for (int r = 0; r < RBF; ++r) {
        float u = d - (float)r * step;
        float rb = expf(coeff * u * u);
        t0 = fmaf(rb, f1[r * H + h0], t0);
        t1 = fmaf(rb, f1[r * H + h1], t1);
    }
    t0 = tanhf(t0); t1 = tanhf(t1);

    float w0 = fb2[blk * H + h0], w1v = fb2[blk * H + h1];
    #pragma unroll 8
    for (int k = 0; k < 64; ++k) {
        float bb = __shfl(t0, k, 64);
        w0  = fmaf(bb, f2[k * H + h0], w0);
        w1v = fmaf(bb, f2[k * H + h1], w1v);
    }
    #pragma unroll 8
    for (int k = 0; k < 64; ++k) {
        float bb = __shfl(t1, k, 64);
        w0  = fmaf(bb, f2[(64 + k) * H + h0], w0);
        w1v = fmaf(bb, f2[(64 + k) * H + h1], w1v);
    }
    float* row = tab + ((size_t)blk * (QT + 1) + q) * H;
    row[h0] = w0 * cenv;
    row[h1] = w1v * cenv;
}

// ---------------------------------------------------------------------------
// Per-edge scatter over segmented edge arrays — DENSE iteration.
// Block computes 16-entry prefix of seg_cnt once; dense index -> segment via
// unrolled compare-accumulate (no division, no empty-slot scan).
__global__ __launch_bounds__(256) void edge_scatter_kernel(
    const int* __restrict__ seg_cnt,
    const int* __restrict__ asrc, const int* __restrict__ adst,
    const float* __restrict__ ad, const float* __restrict__ tab,
    const float* __restrict__ hbuf, float* __restrict__ agg, int CAP)
{
    __shared__ int sbase[SEG + 1];
    const int tid = threadIdx.x;
    if (tid == 0) {
        int run = 0;
        #pragma unroll
        for (int s2 = 0; s2 < SEG; ++s2) { sbase[s2] = run; run += seg_cnt[s2]; }
        sbase[SEG] = run;
    }
    __syncthreads();

    const int lane = tid & 63;
    const int wid = (blockIdx.x * blockDim.x + tid) >> 6;
    const int nw  = (gridDim.x * blockDim.x) >> 6;
    const int total = sbase[SEG];
    const float scale = (float)QT / CUTF;

    for (int i = wid; i < total; i += nw) {
        int seg = 0;
        #pragma unroll
        for (int s2 = 1; s2 < SEG; ++s2) seg += (i >= sbase[s2]) ? 1 : 0;
        int slot = seg * CAP + (i - sbase[seg]);

        int s = asrc[slot], t = adst[slot];
        float p = ad[slot] * scale;
        int i0 = (int)p;
        if (i0 > QT - 1) i0 = QT - 1;
        float f = p - (float)i0;
        const float* r0 = tab + (size_t)i0 * H;
        float wl = fmaf(f, r0[H + lane] - r0[lane], r0[lane]);
        float wh = fmaf(f, r0[H + 64 + lane] - r0[64 + lane], r0[64 + lane]);
        float m0 = hbuf[(size_t)s * H + lane] * wl;
        float m1 = hbuf[(size_t)s * H + 64 + lane] * wh;
        atomicAdd(agg + (size_t)t * H + lane, m0);
        atomicAdd(agg + (size_t)t * H + 64 + lane, m1);
    }
}

// ---------------------------------------------------------------------------
// Role-split: blocks [0,GB): gathered GEMM; [GB,GB+ZB): zero agg rows.
#define GB 512
#define ZB 128
__global__ __launch_bounds__(256) void gemm_rows_zero_kernel(
    const float* __restrict__ A, const float* __restrict__ W,
    float* __restrict__ C,
    const int* __restrict__ rows, const int* __restrict__ cntp,
    float* __restrict__ zbuf, const int* __restrict__ zrows,
    const int* __restrict__ zcntp)
{
    __shared__ float As[32][36];
    __shared__ float Ws[32][128];
    __shared__ int rlist[32];

    const int tid = threadIdx.x;

    if (blockIdx.x >= GB) {
        int zcnt = *zcntp;
        int total = zcnt * 32;
        for (int idx = (blockIdx.x - GB) * 256 + tid; idx < total; idx += ZB * 256) {
            int row = idx >> 5, c = (idx & 31) << 2;
            int r = zrows[row];
            *(float4*)(zbuf + (size_t)r * H + c) = make_float4(0.f, 0.f, 0.f, 0.f);
        }
        return;
    }

    const int cnt = *cntp;
    const int r0 = (tid >> 4) * 2;
    const int c0 = (tid & 15) * 4;

    for (int tile = blockIdx.x; tile * 32 < cnt; tile += GB) {
        __syncthreads();
        if (tid < 32) {
            int idx = tile * 32 + tid;
            rlist[tid] = (idx < cnt) ? rows[idx] : -1;
        }
        __syncthreads();

        float acc[2][8];
        #pragma unroll
        for (int j = 0; j < 2; ++j)
            #pragma unroll
            for (int c = 0; c < 8; ++c) acc[j][c] = 0.f;

        for (int kc = 0; kc < H; kc += 32) {
            {
                int lr = tid >> 3;
                int kk = (tid & 7) * 4;
                int r = rlist[lr];
                float4 v = make_float4(0.f, 0.f, 0.f, 0.f);
                if (r >= 0) v = *(const float4*)(A + (size_t)r * H + kc + kk);
                *(float4*)&As[lr][kk] = v;
            }
            {
                int wr = tid >> 5;
                int wc = (tid & 31) * 4;
                #pragma unroll
                for (int p = 0; p < 4; ++p) {
                    int row = wr + p * 8;
                    *(float4*)&Ws[row][wc] = *(const float4*)(W + (size_t)(kc + row) * H + wc);
                }
            }
            __syncthreads();
            #pragma unroll
            for (int k = 0; k < 32; k += 4) {
                float a_[2][4];
                #pragma unroll
                for (int j = 0; j < 2; ++j)
                    *(float4*)a_[j] = *(const float4*)&As[r0 + j][k];
                #pragma unroll
                for (int kk = 0; kk < 4; ++kk) {
                    float4 wlo = *(const float4*)&Ws[k + kk][c0];
                    float4 whi = *(const float4*)&Ws[k + kk][c0 + 64];
                    float w_[8] = {wlo.x, wlo.y, wlo.z, wlo.w, whi.x, whi.y, whi.z, whi.w};
                    #pragma unroll
                    for (int j = 0; j < 2; ++j)
                        #pragma unroll
                        for (int c = 0; c < 8; ++c)
                            acc[j][c] = fmaf(a_[j][kk], w_[c], acc[j][c]);
                }
            }
            __syncthreads();
        }
        #pragma unroll
        for (int j = 0; j < 2; ++j) {
            int r = rlist[r0 + j];
            if (r < 0) continue;
            #pragma unroll
            for (int hh = 0; hh < 2; ++hh) {
                int cb = c0 + hh * 64;
                *(float4*)(C + (size_t)r * H + cb) = make_float4(
                    acc[j][hh * 4 + 0], acc[j][hh * 4 + 1],
                    acc[j][hh * 4 + 2], acc[j][hh * 4 + 3]);
            }
        }
    }
}

// ---------------------------------------------------------------------------
// Role-split x update: [0,UB) dst GEMM path; [UB,UB+AB) nondst cvec add.
#define UB 512
#define AB 256
__global__ __launch_bounds__(256) void update_x_kernel(
    const float* __restrict__ agg, const float* __restrict__ l2w,
    const float* __restrict__ l2b, const float* __restrict__ bw,
    const float* __restrict__ bb, float* __restrict__ x,
    const int* __restrict__ rows, const int* __restrict__ cntp,
    const int* __restrict__ nrows, const int* __restrict__ ncntp,
    const float* __restrict__ cvec)
{
    __shared__ float As[32][36];
    __shared__ float Ws[32][128];
    __shared__ float Tl[32][132];
    __shared__ int rlist[32];

    const int tid = threadIdx.x;

    if (blockIdx.x >= UB) {
        int ncnt = *ncntp;
        int total = ncnt * 32;
        for (int idx = (blockIdx.x - UB) * 256 + tid; idx < total; idx += AB * 256) {
            int row = idx >> 5, c = (idx & 31) << 2;
            int r = nrows[row];
            float4 v = *(const float4*)(x + (size_t)r * H + c);
            float4 cv = *(const float4*)(cvec + c);
            v.x += cv.x; v.y += cv.y; v.z += cv.z; v.w += cv.w;
            *(float4*)(x + (size_t)r * H + c) = v;
        }
        return;
    }

    const int cnt = *cntp;
    const int r0 = (tid >> 4) * 2;
    const int c0 = (tid & 15) * 4;

    for (int tile = blockIdx.x; tile * 32 < cnt; tile += UB) {
        __syncthreads();
        if (tid < 32) {
            int idx = tile * 32 + tid;
            rlist[tid] = (idx < cnt) ? rows[idx] : -1;
        }
        __syncthreads();

        float acc[2][8];
        #pragma unroll
        for (int j = 0; j < 2; ++j)
            #pragma unroll
            for (int c = 0; c < 8; ++c) acc[j][c] = 0.f;

        for (int kc = 0; kc < H; kc += 32) {
            {
                int lr = tid >> 3;
                int kk = (tid & 7) * 4;
                int r = rlist[lr];
                float4 v = make_float4(0.f, 0.f, 0.f, 0.f);
                if (r >= 0) v = *(const float4*)(agg + (size_t)r * H + kc + kk);
                *(float4*)&As[lr][kk] = v;
            }
            {
                int wr = tid >> 5;
                int wc = (tid & 31) * 4;
                #pragma unroll
                for (int p = 0; p < 4; ++p) {
                    int row = wr + p * 8;
                    *(float4*)&Ws[row][wc] = *(const float4*)(l2w + (size_t)(kc + row) * H + wc);
                }
            }
            __syncthreads();
            #pragma unroll
            for (int k = 0; k < 32; k += 4) {
                float a_[2][4];
                #pragma unroll
                for (int j = 0; j < 2; ++j)
                    *(float4*)a_[j] = *(const float4*)&As[r0 + j][k];
                #pragma unroll
                for (int kk = 0; kk < 4; ++kk) {
                    float4 wlo = *(const float4*)&Ws[k + kk][c0];
                    float4 whi = *(const float4*)&Ws[k + kk][c0 + 64];
                    float w_[8] = {wlo.x, wlo.y, wlo.z, wlo.w, whi.x, whi.y, whi.z, whi.w};
                    #pragma unroll
                    for (int j = 0; j < 2; ++j)
                        #pragma unroll
                        for (int c = 0; c < 8; ++c)
                            acc[j][c] = fmaf(a_[j][kk], w_[c], acc[j][c]);
                }
            }
            __syncthreads();
        }
        #pragma unroll
        for (int j = 0; j < 2; ++j) {
            float4 lo, hi;
            lo.x = tanhf(acc[j][0] + l2b[c0]);      lo.y = tanhf(acc[j][1] + l2b[c0 + 1]);
            lo.z = tanhf(acc[j][2] + l2b[c0 + 2]);  lo.w = tanhf(acc[j][3] + l2b[c0 + 3]);
            hi.x = tanhf(acc[j][4] + l2b[c0 + 64]); hi.y = tanhf(acc[j][5] + l2b[c0 + 65]);
            hi.z = tanhf(acc[j][6] + l2b[c0 + 66]); hi.w = tanhf(acc[j][7] + l2b[c0 + 67]);
            *(float4*)&Tl[r0 + j][c0] = lo;
            *(float4*)&Tl[r0 + j][c0 + 64] = hi;
        }

        float acc2[2][8];
        #pragma unroll
        for (int j = 0; j < 2; ++j)
            #pragma unroll
            for (int c = 0; c < 8; ++c) acc2[j][c] = 0.f;

        for (int kc = 0; kc < H; kc += 32) {
            __syncthreads();
            {
                int wr = tid >> 5;
                int wc = (tid & 31) * 4;
                #pragma unroll
                for (int p = 0; p < 4; ++p) {
                    int row = wr + p * 8;
                    *(float4*)&Ws[row][wc] = *(const float4*)(bw + (size_t)(kc + row) * H + wc);
                }
            }
            __syncthreads();
            #pragma unroll
            for (int k = 0; k < 32; k += 4) {
                float a_[2][4];
                #pragma unroll
                for (int j = 0; j < 2; ++j)
                    *(float4*)a_[j] = *(const float4*)&Tl[r0 + j][kc + k];
                #pragma unroll
                for (int kk = 0; kk < 4; ++kk) {
                    float4 wlo = *(const float4*)&Ws[k + kk][c0];
                    float4 whi = *(const float4*)&Ws[k + kk][c0 + 64];
                    float w_[8] = {wlo.x, wlo.y, wlo.z, wlo.w, whi.x, whi.y, whi.z, whi.w};
                    #pragma unroll
                    for (int j = 0; j < 2; ++j)
                        #pragma unroll
                        for (int c = 0; c < 8; ++c)
                            acc2[j][c] = fmaf(a_[j][kk], w_[c], acc2[j][c]);
                }
            }
        }
        #pragma unroll
        for (int j = 0; j < 2; ++j) {
            int r = rlist[r0 + j];
            if (r < 0) continue;
            #pragma unroll
            for (int hh = 0; hh < 2; ++hh) {
                int cb = c0 + hh * 64;
                float4 xv = *(const float4*)(x + (size_t)r * H + cb);
                xv.x += acc2[j][hh * 4 + 0] + bb[cb];
                xv.y += acc2[j][hh * 4 + 1] + bb[cb + 1];
                xv.z += acc2[j][hh * 4 + 2] + bb[cb + 2];
                xv.w += acc2[j][hh * 4 + 3] + bb[cb + 3];
                *(float4*)(x + (size_t)r * H + cb) = xv;
            }
        }
    }
}

// ---------------------------------------------------------------------------
__global__ __launch_bounds__(256) void out_head_kernel(
    const float* __restrict__ x, const int* __restrict__ batch,
    const float* __restrict__ w1, const float* __restrict__ b1,
    const float* __restrict__ w2, const float* __restrict__ b2,
    float* __restrict__ energy, int Nn)
{
    __shared__ float As[64][33];
    __shared__ float Ws[32][68];
    __shared__ float e_lds[64];
    __shared__ int   gid_lds[64];

    const int tid = threadIdx.x;
    const int m0 = blockIdx.x * 64;
    const int r0 = (tid >> 4) * 4;
    const int c0 = (tid & 15) * 4;

    float acc[4][4];
    #pragma unroll
    for (int j = 0; j < 4; ++j)
        #pragma unroll
        for (int c = 0; c < 4; ++c) acc[j][c] = 0.0f;

    for (int kc = 0; kc < 128; kc += 32) {
        {
            int r = tid >> 3;
            int kk = (tid & 7) * 4;
            #pragma unroll
            for (int p = 0; p < 2; ++p) {
                int row = r + p * 32;
                float4 v = make_float4(0.f, 0.f, 0.f, 0.f);
                if (m0 + row < Nn) v = *(const float4*)(x + (size_t)(m0 + row) * H + kc + kk);
                As[row][kk] = v.x; As[row][kk + 1] = v.y;
                As[row][kk + 2] = v.z; As[row][kk + 3] = v.w;
            }
        }
        {
            int wr = tid >> 4;
            int wc = (tid & 15) * 4;
            #pragma unroll
            for (int p = 0; p < 2; ++p) {
                int row = wr + p * 16;
                *(float4*)&Ws[row][wc] = *(const float4*)(w1 + (size_t)(kc + row) * 64 + wc);
            }
        }
        __syncthreads();
        #pragma unroll
        for (int k = 0; k < 32; ++k) {
            float a_[4];
            #pragma unroll
            for (int j = 0; j < 4; ++j) a_[j] = As[r0 + j][k];
            float4 wv = *(float4*)&Ws[k][c0];
            float w_[4] = {wv.x, wv.y, wv.z, wv.w};
            #pragma unroll
            for (int j = 0; j < 4; ++j)
                #pragma unroll
                for (int c = 0; c < 4; ++c)
                    acc[j][c] = fmaf(a_[j], w_[c], acc[j][c]);
        }
        __syncthreads();
    }

    const float4 b1v = *(const float4*)(b1 + c0);
    const float4 w2v = *(const float4*)(w2 + c0);
    float ep[4];
    #pragma unroll
    for (int j = 0; j < 4; ++j) {
        float v0 = tanhf(acc[j][0] + b1v.x);
        float v1 = tanhf(acc[j][1] + b1v.y);
        float v2 = tanhf(acc[j][2] + b1v.z);
        float v3 = tanhf(acc[j][3] + b1v.w);
        ep[j] = v0 * w2v.x + v1 * w2v.y + v2 * w2v.z + v3 * w2v.w;
    }
    #pragma unroll
    for (int off = 1; off < 16; off <<= 1) {
        #pragma unroll
        for (int j = 0; j < 4; ++j) ep[j] += __shfl_xor(ep[j], off, 64);
    }
    if ((tid & 15) == 0) {
        const float b2v = b2[0];
        #pragma unroll
        for (int j = 0; j < 4; ++j) e_lds[r0 + j] = ep[j] + b2v;
    }
    if (tid < 64) {
        int row = m0 + tid;
        gid_lds[tid] = (row < Nn) ? batch[row] : -1;
    }
    __syncthreads();

    if (tid == 0) {
        int cur = -1; float sum = 0.0f;
        for (int r = 0; r < 64; ++r) {
            int g = gid_lds[r];
            if (g < 0) continue;
            if (g != cur) {
                if (cur >= 0) atomicAdd(&energy[cur], sum);
                cur = g; sum = 0.0f;
            }
            sum += e_lds[r];
        }
        if (cur >= 0) atomicAdd(&energy[cur], sum);
    }
}

// ---------------------------------------------------------------------------
extern "C" void kernel_launch(void* const* d_in, const int* in_sizes, int n_in,
                              void* d_out, int out_size, void* d_ws, size_t ws_size,
                              hipStream_t stream)
{
    const int*   atype = (const int*)  d_in[0];
    const float* pos   = (const float*)d_in[1];
    const int*   ei    = (const int*)  d_in[2];
    const int*   batch = (const int*)  d_in[3];
    const float* emb   = (const float*)d_in[4];
    const float* fw1   = (const float*)d_in[5];
    const float* fb1   = (const float*)d_in[6];
    const float* fw2   = (const float*)d_in[7];
    const float* fb2   = (const float*)d_in[8];
    const float* lin1w = (const float*)d_in[9];
    const float* lin2w = (const float*)d_in[10];
    const float* lin2b = (const float*)d_in[11];
    const float* blkw  = (const float*)d_in[12];
    const float* blkb  = (const float*)d_in[13];
    const float* ow1   = (const float*)d_in[14];
    const float* ob1   = (const float*)d_in[15];
    const float* ow2   = (const float*)d_in[16];
    const float* ob2   = (const float*)d_in[17];

    const int Nn = in_sizes[0];
    const int E  = in_sizes[2] / 2;
    float* energy = (float*)d_out;

    // edge segmentation geometry
    const int eblocks = (E + 1023) / 1024;                // 4 edges/thread, 256 thr
    const int bps = (eblocks + SEG - 1) / SEG;
    const int CAP = bps * 1024;                           // per-segment capacity
    const int SEGCAP = SEG * CAP;

    // workspace layout: cnt/seg_cnt + flags contiguous -> single memset
    char* w = (char*)d_ws;
    int*   cnt  = (int*)w;           // [1]=src [2]=dst [3]=nondst ; [8..23]=seg_cnt
    int*   seg_cnt = cnt + 8;
    int*   is_src = (int*)(w + 256);                    // N
    int*   is_dst = is_src + Nn;                        // N
    float* x    = (float*)(is_dst + Nn);                // N*H
    float* hbuf = x + (size_t)Nn * H;                   // N*H
    float* agg  = hbuf + (size_t)Nn * H;                // N*H
    int*   asrc = (int*)(agg + (size_t)Nn * H);         // SEGCAP
    int*   adst = asrc + SEGCAP;                        // SEGCAP
    float* ad   = (float*)(adst + SEGCAP);              // SEGCAP
    int*   src_list = (int*)(ad + SEGCAP);              // N
    int*   dst_list = src_list + Nn;                    // N
    int*   nondst_list = dst_list + Nn;                 // N
    float* cvec = (float*)(nondst_list + Nn);           // 2*H
    float* tab  = cvec + 2 * H;                         // 2*(QT+1)*H
    float4* pos4 = (float4*)(tab + 2 * (size_t)(QT + 1) * H);  // N

    hipMemsetAsync(cnt, 0, 256 + 2 * (size_t)Nn * sizeof(int), stream);
    hipMemsetAsync(energy, 0, (size_t)out_size * sizeof(float), stream);

    {
        int XB = (Nn * 32 + 255) / 256;
        int PB = (Nn + 255) / 256;
        init_pos_x_kernel<<<XB + PB, 256, 0, stream>>>(atype, emb, pos, x, pos4, Nn, XB);
    }
    edge_prep_kernel<<<eblocks, 256, 0, stream>>>(
        pos4, ei, E, CAP, seg_cnt, asrc, adst, ad, is_src, is_dst);
    compact_atoms_kernel<<<(Nn + 255) / 256, 256, 0, stream>>>(
        is_src, is_dst, Nn, cnt, src_list, dst_list, nondst_list);
    {
        int waves = 2 * (QT + 1) + 2;
        filter_table_kernel<<<(waves + 3) / 4, 256, 0, stream>>>(
            fw1, fb1, fw2, fb2, lin2b, blkw, blkb, tab, cvec);
    }

    for (int i = 0; i < 2; ++i) {
        const float* l1w  = lin1w + (size_t)i * H * H;
        const float* l2w  = lin2w + (size_t)i * H * H;
        const float* l2b  = lin2b + (size_t)i * H;
        const float* bw   = blkw + (size_t)i * H * H;
        const float* bb   = blkb + (size_t)i * H;
        const float* tabi = tab + (size_t)i * (QT + 1) * H;

        gemm_rows_zero_kernel<<<GB + ZB, 256, 0, stream>>>(
            x, l1w, hbuf, src_list, cnt + 1, agg, dst_list, cnt + 2);
        edge_scatter_kernel<<<1024, 256, 0, stream>>>(seg_cnt, asrc, adst, ad,
                                                      tabi, hbuf, agg, CAP);
        update_x_kernel<<<UB + AB, 256, 0, stream>>>(
            agg, l2w, l2b, bw, bb, x, dst_list, cnt + 2,
            nondst_list, cnt + 3, cvec + i * H);
    }

    out_head_kernel<<<(Nn + 63) / 64, 256, 0, stream>>>(x, batch, ow1, ob1, ow2, ob2, energy, Nn);
}

// Round 9
// 235.526 us; speedup vs baseline: 1.5108x; 1.0645x over previous
//
#include <hip/hip_runtime.h>
#include <hip/hip_bf16.h>
#include <math.h>

#define H 128
#define RBF 50
#define CUTF 5.0f
#define PIF 3.14159265358979323846f
#define QT 1024                       // filter table intervals (QT+1 knots)
#define SEG 16                        // edge-compaction segments

// ---------------------------------------------------------------------------
// Prep mega-kernel, role-split by block ranges:
//  [0,ZFB)        zero counters + is_src/is_dst flags
//  [ZFB,+PB)      pos4[n] = {x,y,z,0}
//  [.. ,+FB)      filter table (2*(QT+1) waves) + cvec (2 waves)
//  [.. ,+TB)      e_type[t] = head(emb[t] + cvec0 + cvec1)  (one wave per type)
__global__ __launch_bounds__(256) void prep_kernel(
    const float* __restrict__ pos, float4* __restrict__ pos4, int Nn,
    int4* __restrict__ zbase, int zquads,
    const float* __restrict__ fw1, const float* __restrict__ fb1,
    const float* __restrict__ fw2, const float* __restrict__ fb2,
    const float* __restrict__ lin2b, const float* __restrict__ blkw,
    const float* __restrict__ blkb, const float* __restrict__ emb,
    const float* __restrict__ ow1, const float* __restrict__ ob1,
    const float* __restrict__ ow2, const float* __restrict__ ob2,
    float* __restrict__ tab, float* __restrict__ cvec,
    float* __restrict__ e_type, int NT,
    int ZFB, int PB, int FB)
{
    int b = blockIdx.x;
    const int tid = threadIdx.x;
    const int lane = tid & 63;

    if (b < ZFB) {
        int i = b * 256 + tid;
        if (i < zquads) zbase[i] = make_int4(0, 0, 0, 0);
        return;
    }
    b -= ZFB;
    if (b < PB) {
        int n = b * 256 + tid;
        if (n < Nn)
            pos4[n] = make_float4(pos[3 * n], pos[3 * n + 1], pos[3 * n + 2], 0.0f);
        return;
    }
    b -= PB;
    const int h0 = lane, h1 = lane + 64;
    if (b < FB) {
        const int wid = b * 4 + (tid >> 6);
        const int ntab = 2 * (QT + 1);
        if (wid >= ntab + 2) return;
        if (wid >= ntab) {
            // cvec task
            const int blk = wid - ntab;
            const float* bwp = blkw + (size_t)blk * H * H;
            float t0 = tanhf(lin2b[blk * H + h0]);
            float t1 = tanhf(lin2b[blk * H + h1]);
            float a0 = blkb[blk * H + h0], a1 = blkb[blk * H + h1];
            #pragma unroll 8
            for (int k = 0; k < 64; ++k) {
                float bb2 = __shfl(t0, k, 64);
                a0 = fmaf(bb2, bwp[k * H + h0], a0);
                a1 = fmaf(bb2, bwp[k * H + h1], a1);
            }
            #pragma unroll 8
            for (int k = 0; k < 64; ++k) {
                float bb2 = __shfl(t1, k, 64);
                a0 = fmaf(bb2, bwp[(64 + k) * H + h0], a0);
                a1 = fmaf(bb2, bwp[(64 + k) * H + h1], a1);
            }
            cvec[blk * H + h0] = a0;
            cvec[blk * H + h1] = a1;
            return;
        }
        const int blk = wid / (QT + 1);
        const int q = wid - blk * (QT + 1);
        const float d = (float)q * (CUTF / (float)QT);
        const float* f1 = fw1 + (size_t)blk * RBF * H;
        const float* f2 = fw2 + (size_t)blk * H * H;
        const float step  = CUTF / 49.0f;
        const float coeff = -0.5f / (step * step);
        float cenv = (d < CUTF) ? 0.5f * (cosf(d * (PIF / CUTF)) + 1.0f) : 0.0f;

        float t0 = fb1[blk * H + h0], t1 = fb1[blk * H + h1];
        #pragma unroll
        for (int r = 0; r < RBF; ++r) {
            float u = d - (float)r * step;
            float rb = expf(coeff * u * u);
            t0 = fmaf(rb, f1[r * H + h0], t0);
            t1 = fmaf(rb, f1[r * H + h1], t1);
        }
        t0 = tanhf(t0); t1 = tanhf(t1);
        float w0 = fb2[blk * H + h0], w1v = fb2[blk * H + h1];
        #pragma unroll 8
        for (int k = 0; k < 64; ++k) {
            float bb2 = __shfl(t0, k, 64);
            w0  = fmaf(bb2, f2[k * H + h0], w0);
            w1v = fmaf(bb2, f2[k * H + h1], w1v);
        }
        #pragma unroll 8
        for (int k = 0; k < 64; ++k) {
            float bb2 = __shfl(t1, k, 64);
            w0  = fmaf(bb2, f2[(64 + k) * H + h0], w0);
            w1v = fmaf(bb2, f2[(64 + k) * H + h1], w1v);
        }
        float* row = tab + ((size_t)blk * (QT + 1) + q) * H;
        row[h0] = w0 * cenv;
        row[h1] = w1v * cenv;
        return;
    }
    b -= FB;
    // e_type role: one wave per atom type
    const int ty = b * 4 + (tid >> 6);
    if (ty >= NT) return;
    float xt0 = emb[(size_t)ty * H + h0];
    float xt1 = emb[(size_t)ty * H + h1];
    #pragma unroll
    for (int blk = 0; blk < 2; ++blk) {
        const float* bwp = blkw + (size_t)blk * H * H;
        float t0 = tanhf(lin2b[blk * H + h0]);
        float t1 = tanhf(lin2b[blk * H + h1]);
        float a0 = blkb[blk * H + h0], a1 = blkb[blk * H + h1];
        #pragma unroll 8
        for (int k = 0; k < 64; ++k) {
            float bb2 = __shfl(t0, k, 64);
            a0 = fmaf(bb2, bwp[k * H + h0], a0);
            a1 = fmaf(bb2, bwp[k * H + h1], a1);
        }
        #pragma unroll 8
        for (int k = 0; k < 64; ++k) {
            float bb2 = __shfl(t1, k, 64);
            a0 = fmaf(bb2, bwp[(64 + k) * H + h0], a0);
            a1 = fmaf(bb2, bwp[(64 + k) * H + h1], a1);
        }
        xt0 += a0; xt1 += a1;
    }
    // output head GEMV: lane = column (64 cols)
    float y = ob1[lane];
    #pragma unroll 8
    for (int k = 0; k < 64; ++k) {
        float bb2 = __shfl(xt0, k, 64);
        y = fmaf(bb2, ow1[k * 64 + lane], y);
    }
    #pragma unroll 8
    for (int k = 0; k < 64; ++k) {
        float bb2 = __shfl(xt1, k, 64);
        y = fmaf(bb2, ow1[(64 + k) * 64 + lane], y);
    }
    y = tanhf(y) * ow2[lane];
    #pragma unroll
    for (int off = 32; off; off >>= 1) y += __shfl_xor(y, off, 64);
    if (lane == 0) e_type[ty] = y + ob2[0];
}

// ---------------------------------------------------------------------------
// Edge compaction, 4 edges/thread, block-aggregated atomic into SEG counters.
__global__ __launch_bounds__(256) void edge_prep_kernel(
    const float4* __restrict__ pos4, const int* __restrict__ ei, int E, int CAP,
    int* __restrict__ seg_cnt, int* __restrict__ asrc, int* __restrict__ adst,
    float* __restrict__ ad, int* __restrict__ is_src, int* __restrict__ is_dst)
{
    __shared__ int wtot[4], wbase[4];
    const int tid = threadIdx.x;
    const int lane = tid & 63;
    const int wv = tid >> 6;
    const int gtid = blockIdx.x * 256 + tid;

    int s[4], t[4];
    float d[4];
    bool act[4] = {false, false, false, false};

    const int e0 = gtid * 4;
    if (e0 + 3 < E && (E & 3) == 0) {
        const int4 sv = *(const int4*)(ei + e0);
        const int4 tv = *(const int4*)(ei + E + e0);
        s[0] = sv.x; s[1] = sv.y; s[2] = sv.z; s[3] = sv.w;
        t[0] = tv.x; t[1] = tv.y; t[2] = tv.z; t[3] = tv.w;
        #pragma unroll
        for (int j = 0; j < 4; ++j) {
            float4 ps = pos4[s[j]], pt = pos4[t[j]];
            float dx = ps.x - pt.x, dy = ps.y - pt.y, dz = ps.z - pt.z;
            d[j] = sqrtf(dx * dx + dy * dy + dz * dz + 1e-12f);
            act[j] = (d[j] < CUTF);
        }
    } else if (e0 < E) {
        #pragma unroll
        for (int j = 0; j < 4; ++j) {
            int e = e0 + j;
            if (e < E) {
                s[j] = ei[e]; t[j] = ei[E + e];
                float4 ps = pos4[s[j]], pt = pos4[t[j]];
                float dx = ps.x - pt.x, dy = ps.y - pt.y, dz = ps.z - pt.z;
                d[j] = sqrtf(dx * dx + dy * dy + dz * dz + 1e-12f);
                act[j] = (d[j] < CUTF);
            }
        }
    }

    unsigned long long b[4];
    int mytot = 0;
    #pragma unroll
    for (int j = 0; j < 4; ++j) {
        b[j] = __ballot(act[j]);
        mytot += (int)__popcll(b[j]);
    }
    if (lane == 0) wtot[wv] = mytot;
    __syncthreads();
    if (tid == 0) {
        int t0 = wtot[0], t1 = wtot[1], t2 = wtot[2], t3 = wtot[3];
        int tot = t0 + t1 + t2 + t3;
        int base = 0;
        if (tot) base = atomicAdd(&seg_cnt[blockIdx.x & (SEG - 1)], tot);
        wbase[0] = base; wbase[1] = base + t0;
        wbase[2] = base + t0 + t1; wbase[3] = base + t0 + t1 + t2;
    }
    __syncthreads();

    int run = wbase[wv];
    const int segoff = (int)(blockIdx.x & (SEG - 1)) * CAP;
    const unsigned long long ltm = ((unsigned long long)1 << lane) - 1;
    #pragma unroll
    for (int j = 0; j < 4; ++j) {
        if (act[j]) {
            int p = segoff + run + (int)__popcll(b[j] & ltm);
            asrc[p] = s[j]; adst[p] = t[j]; ad[p] = d[j];
            is_src[s[j]] = 1; is_dst[t[j]] = 1;
        }
        run += (int)__popcll(b[j]);
    }
}

// ---------------------------------------------------------------------------
// Atom lists: [1]=src, [2]=dst, [3]=src&&!dst. Block-aggregated atomics.
__global__ __launch_bounds__(256) void compact_atoms_kernel(
    const int* __restrict__ is_src, const int* __restrict__ is_dst, int Nn,
    int* __restrict__ cnt4,
    int* __restrict__ src_list, int* __restrict__ dst_list, int* __restrict__ sn_list)
{
    __shared__ int wtot[3][4], wbase[3][4];
    const int tid = threadIdx.x;
    const int lane = tid & 63;
    const int wv = tid >> 6;
    int n = blockIdx.x * 256 + tid;
    bool v[3] = {false, false, false};
    if (n < Nn) {
        v[0] = is_src[n] != 0;
        v[1] = is_dst[n] != 0;
        v[2] = v[0] && !v[1];
    }
    unsigned long long b[3];
    #pragma unroll
    for (int l = 0; l < 3; ++l) {
        b[l] = __ballot(v[l]);
        if (lane == 0) wtot[l][wv] = (int)__popcll(b[l]);
    }
    __syncthreads();
    if (tid == 0) {
        #pragma unroll
        for (int l = 0; l < 3; ++l) {
            int t0 = wtot[l][0], t1 = wtot[l][1], t2 = wtot[l][2], t3 = wtot[l][3];
            int tot = t0 + t1 + t2 + t3;
            int base = 0;
            if (tot) base = atomicAdd(cnt4 + 1 + l, tot);
            wbase[l][0] = base; wbase[l][1] = base + t0;
            wbase[l][2] = base + t0 + t1; wbase[l][3] = base + t0 + t1 + t2;
        }
    }
    __syncthreads();
    const unsigned long long ltm = ((unsigned long long)1 << lane) - 1;
    if (v[0]) src_list[wbase[0][wv] + (int)__popcll(b[0] & ltm)] = n;
    if (v[1]) dst_list[wbase[1][wv] + (int)__popcll(b[1] & ltm)] = n;
    if (v[2]) sn_list[wbase[2][wv] + (int)__popcll(b[2] & ltm)] = n;
}

// ---------------------------------------------------------------------------
// Per-edge scatter over segmented edge arrays — dense iteration.
__global__ __launch_bounds__(256) void edge_scatter_kernel(
    const int* __restrict__ seg_cnt,
    const int* __restrict__ asrc, const int* __restrict__ adst,
    const float* __restrict__ ad, const float* __restrict__ tab,
    const float* __restrict__ hbuf, float* __restrict__ agg, int CAP)
{
    __shared__ int sbase[SEG + 1];
    const int tid = threadIdx.x;
    if (tid == 0) {
        int run = 0;
        #pragma unroll
        for (int s2 = 0; s2 < SEG; ++s2) { sbase[s2] = run; run += seg_cnt[s2]; }
        sbase[SEG] = run;
    }
    __syncthreads();

    const int lane = tid & 63;
    const int wid = (blockIdx.x * blockDim.x + tid) >> 6;
    const int nw  = (gridDim.x * blockDim.x) >> 6;
    const int total = sbase[SEG];
    const float scale = (float)QT / CUTF;

    for (int i = wid; i < total; i += nw) {
        int seg = 0;
        #pragma unroll
        for (int s2 = 1; s2 < SEG; ++s2) seg += (i >= sbase[s2]) ? 1 : 0;
        int slot = seg * CAP + (i - sbase[seg]);

        int s = asrc[slot], t = adst[slot];
        float p = ad[slot] * scale;
        int i0 = (int)p;
        if (i0 > QT - 1) i0 = QT - 1;
        float f = p - (float)i0;
        const float* r0 = tab + (size_t)i0 * H;
        float wl = fmaf(f, r0[H + lane] - r0[lane], r0[lane]);
        float wh = fmaf(f, r0[H + 64 + lane] - r0[64 + lane], r0[64 + lane]);
        float m0 = hbuf[(size_t)s * H + lane] * wl;
        float m1 = hbuf[(size_t)s * H + 64 + lane] * wh;
        atomicAdd(agg + (size_t)t * H + lane, m0);
        atomicAdd(agg + (size_t)t * H + 64 + lane, m1);
    }
}

// ---------------------------------------------------------------------------
// Role-split: [0,GB) gathered GEMM (A row = emb[atype[r]] if atype!=null else
// A[r]); [GB,GB+ZB) zero agg rows in zrows.
#define GB 512
#define ZB 128
__global__ __launch_bounds__(256) void gemm_rows_zero_kernel(
    const float* __restrict__ A, const int* __restrict__ atype,
    const float* __restrict__ emb, const float* __restrict__ W,
    float* __restrict__ C,
    const int* __restrict__ rows, const int* __restrict__ cntp,
    float* __restrict__ zbuf, const int* __restrict__ zrows,
    const int* __restrict__ zcntp)
{
    __shared__ float As[32][36];
    __shared__ float Ws[32][128];
    __shared__ int rlist[32], tlist[32];

    const int tid = threadIdx.x;

    if (blockIdx.x >= GB) {
        int zcnt = *zcntp;
        int total = zcnt * 32;
        for (int idx = (blockIdx.x - GB) * 256 + tid; idx < total; idx += ZB * 256) {
            int row = idx >> 5, c = (idx & 31) << 2;
            int r = zrows[row];
            *(float4*)(zbuf + (size_t)r * H + c) = make_float4(0.f, 0.f, 0.f, 0.f);
        }
        return;
    }

    const int cnt = *cntp;
    const int r0 = (tid >> 4) * 2;
    const int c0 = (tid & 15) * 4;

    for (int tile = blockIdx.x; tile * 32 < cnt; tile += GB) {
        __syncthreads();
        if (tid < 32) {
            int idx = tile * 32 + tid;
            int r = (idx < cnt) ? rows[idx] : -1;
            rlist[tid] = r;
            tlist[tid] = (atype && r >= 0) ? atype[r] : 0;
        }
        __syncthreads();

        float acc[2][8];
        #pragma unroll
        for (int j = 0; j < 2; ++j)
            #pragma unroll
            for (int c = 0; c < 8; ++c) acc[j][c] = 0.f;

        for (int kc = 0; kc < H; kc += 32) {
            {
                int lr = tid >> 3;
                int kk = (tid & 7) * 4;
                int r = rlist[lr];
                float4 v = make_float4(0.f, 0.f, 0.f, 0.f);
                if (r >= 0) {
                    const float* base = atype ? (emb + (size_t)tlist[lr] * H)
                                              : (A + (size_t)r * H);
                    v = *(const float4*)(base + kc + kk);
                }
                *(float4*)&As[lr][kk] = v;
            }
            {
                int wr = tid >> 5;
                int wc = (tid & 31) * 4;
                #pragma unroll
                for (int p = 0; p < 4; ++p) {
                    int row = wr + p * 8;
                    *(float4*)&Ws[row][wc] = *(const float4*)(W + (size_t)(kc + row) * H + wc);
                }
            }
            __syncthreads();
            #pragma unroll
            for (int k = 0; k < 32; k += 4) {
                float a_[2][4];
                #pragma unroll
                for (int j = 0; j < 2; ++j)
                    *(float4*)a_[j] = *(const float4*)&As[r0 + j][k];
                #pragma unroll
                for (int kk = 0; kk < 4; ++kk) {
                    float4 wlo = *(const float4*)&Ws[k + kk][c0];
                    float4 whi = *(const float4*)&Ws[k + kk][c0 + 64];
                    float w_[8] = {wlo.x, wlo.y, wlo.z, wlo.w, whi.x, whi.y, whi.z, whi.w};
                    #pragma unroll
                    for (int j = 0; j < 2; ++j)
                        #pragma unroll
                        for (int c = 0; c < 8; ++c)
                            acc[j][c] = fmaf(a_[j][kk], w_[c], acc[j][c]);
                }
            }
            __syncthreads();
        }
        #pragma unroll
        for (int j = 0; j < 2; ++j) {
            int r = rlist[r0 + j];
            if (r < 0) continue;
            #pragma unroll
            for (int hh = 0; hh < 2; ++hh) {
                int cb = c0 + hh * 64;
                *(float4*)(C + (size_t)r * H + cb) = make_float4(
                    acc[j][hh * 4 + 0], acc[j][hh * 4 + 1],
                    acc[j][hh * 4 + 2], acc[j][hh * 4 + 3]);
            }
        }
    }
}

// ---------------------------------------------------------------------------
// Block-0 update: [0,UB) x[dst] = emb[atype]+tanh(agg@l2w+l2b)@bw+bb;
//                 [UB,UB+AB) x[src&&!dst] = emb[atype] + cvec0
#define UB 512
#define AB 128
__global__ __launch_bounds__(256) void update_x0_kernel(
    const float* __restrict__ agg, const float* __restrict__ l2w,
    const float* __restrict__ l2b, const float* __restrict__ bw,
    const float* __restrict__ bb, float* __restrict__ x,
    const float* __restrict__ emb, const int* __restrict__ atype,
    const int* __restrict__ rows, const int* __restrict__ cntp,
    const int* __restrict__ snrows, const int* __restrict__ sncntp,
    const float* __restrict__ cvec0)
{
    __shared__ float As[32][36];
    __shared__ float Ws[32][128];
    __shared__ float Tl[32][132];
    __shared__ int rlist[32], tlist[32];

    const int tid = threadIdx.x;

    if (blockIdx.x >= UB) {
        int ncnt = *sncntp;
        int total = ncnt * 32;
        for (int idx = (blockIdx.x - UB) * 256 + tid; idx < total; idx += AB * 256) {
            int row = idx >> 5, c = (idx & 31) << 2;
            int r = snrows[row];
            int ty = atype[r];
            float4 ev = *(const float4*)(emb + (size_t)ty * H + c);
            float4 cv = *(const float4*)(cvec0 + c);
            ev.x += cv.x; ev.y += cv.y; ev.z += cv.z; ev.w += cv.w;
            *(float4*)(x + (size_t)r * H + c) = ev;
        }
        return;
    }

    const int cnt = *cntp;
    const int r0 = (tid >> 4) * 2;
    const int c0 = (tid & 15) * 4;

    for (int tile = blockIdx.x; tile * 32 < cnt; tile += UB) {
        __syncthreads();
        if (tid < 32) {
            int idx = tile * 32 + tid;
            int r = (idx < cnt) ? rows[idx] : -1;
            rlist[tid] = r;
            tlist[tid] = (r >= 0) ? atype[r] : 0;
        }
        __syncthreads();

        // phase A: T = tanh(agg @ l2w + l2b)
        float acc[2][8];
        #pragma unroll
        for (int j = 0; j < 2; ++j)
            #pragma unroll
            for (int c = 0; c < 8; ++c) acc[j][c] = 0.f;

        for (int kc = 0; kc < H; kc += 32) {
            {
                int lr = tid >> 3;
                int kk = (tid & 7) * 4;
                int r = rlist[lr];
                float4 v = make_float4(0.f, 0.f, 0.f, 0.f);
                if (r >= 0) v = *(const float4*)(agg + (size_t)r * H + kc + kk);
                *(float4*)&As[lr][kk] = v;
            }
            {
                int wr = tid >> 5;
                int wc = (tid & 31) * 4;
                #pragma unroll
                for (int p = 0; p < 4; ++p) {
                    int row = wr + p * 8;
                    *(float4*)&Ws[row][wc] = *(const float4*)(l2w + (size_t)(kc + row) * H + wc);
                }
            }
            __syncthreads();
            #pragma unroll
            for (int k = 0; k < 32; k += 4) {
                float a_[2][4];
                #pragma unroll
                for (int j = 0; j < 2; ++j)
                    *(float4*)a_[j] = *(const float4*)&As[r0 + j][k];
                #pragma unroll
                for (int kk = 0; kk < 4; ++kk) {
                    float4 wlo = *(const float4*)&Ws[k + kk][c0];
                    float4 whi = *(const float4*)&Ws[k + kk][c0 + 64];
                    float w_[8] = {wlo.x, wlo.y, wlo.z, wlo.w, whi.x, whi.y, whi.z, whi.w};
                    #pragma unroll
                    for (int j = 0; j < 2; ++j)
                        #pragma unroll
                        for (int c = 0; c < 8; ++c)
                            acc[j][c] = fmaf(a_[j][kk], w_[c], acc[j][c]);
                }
            }
            __syncthreads();
        }
        #pragma unroll
        for (int j = 0; j < 2; ++j) {
            float4 lo, hi;
            lo.x = tanhf(acc[j][0] + l2b[c0]);      lo.y = tanhf(acc[j][1] + l2b[c0 + 1]);
            lo.z = tanhf(acc[j][2] + l2b[c0 + 2]);  lo.w = tanhf(acc[j][3] + l2b[c0 + 3]);
            hi.x = tanhf(acc[j][4] + l2b[c0 + 64]); hi.y = tanhf(acc[j][5] + l2b[c0 + 65]);
            hi.z = tanhf(acc[j][6] + l2b[c0 + 66]); hi.w = tanhf(acc[j][7] + l2b[c0 + 67]);
            *(float4*)&Tl[r0 + j][c0] = lo;
            *(float4*)&Tl[r0 + j][c0 + 64] = hi;
        }

        // phase B: x[r] = emb[ty] + T @ bw + bb
        float acc2[2][8];
        #pragma unroll
        for (int j = 0; j < 2; ++j)
            #pragma unroll
            for (int c = 0; c < 8; ++c) acc2[j][c] = 0.f;

        for (int kc = 0; kc < H; kc += 32) {
            __syncthreads();
            {
                int wr = tid >> 5;
                int wc = (tid & 31) * 4;
                #pragma unroll
                for (int p = 0; p < 4; ++p) {
                    int row = wr + p * 8;
                    *(float4*)&Ws[row][wc] = *(const float4*)(bw + (size_t)(kc + row) * H + wc);
                }
            }
            __syncthreads();
            #pragma unroll
            for (int k = 0; k < 32; k += 4) {
                float a_[2][4];
                #pragma unroll
                for (int j = 0; j < 2; ++j)
                    *(float4*)a_[j] = *(const float4*)&Tl[r0 + j][kc + k];
                #pragma unroll
                for (int kk = 0; kk < 4; ++kk) {
                    float4 wlo = *(const float4*)&Ws[k + kk][c0];
                    float4 whi = *(const float4*)&Ws[k + kk][c0 + 64];
                    float w_[8] = {wlo.x, wlo.y, wlo.z, wlo.w, whi.x, whi.y, whi.z, whi.w};
                    #pragma unroll
                    for (int j = 0; j < 2; ++j)
                        #pragma unroll
                        for (int c = 0; c < 8; ++c)
                            acc2[j][c] = fmaf(a_[j][kk], w_[c], acc2[j][c]);
                }
            }
        }
        #pragma unroll
        for (int j = 0; j < 2; ++j) {
            int r = rlist[r0 + j];
            if (r < 0) continue;
            int ty = tlist[r0 + j];
            #pragma unroll
            for (int hh = 0; hh < 2; ++hh) {
                int cb = c0 + hh * 64;
                float4 xv = *(const float4*)(emb + (size_t)ty * H + cb);
                xv.x += acc2[j][hh * 4 + 0] + bb[cb];
                xv.y += acc2[j][hh * 4 + 1] + bb[cb + 1];
                xv.z += acc2[j][hh * 4 + 2] + bb[cb + 2];
                xv.w += acc2[j][hh * 4 + 3] + bb[cb + 3];
                *(float4*)(x + (size_t)r * H + cb) = xv;
            }
        }
    }
}

// ---------------------------------------------------------------------------
// Block-1 update fused with output head: computes final x[dst] in LDS, then
// e_atom[r] = tanh(x_final@ow1+ob1)@ow2 + ob2.  x is never written.
__global__ __launch_bounds__(256) void update_e_kernel(
    const float* __restrict__ agg, const float* __restrict__ l2w,
    const float* __restrict__ l2b, const float* __restrict__ bw,
    const float* __restrict__ bb, const float* __restrict__ x,
    const float* __restrict__ ow1, const float* __restrict__ ob1,
    const float* __restrict__ ow2, const float* __restrict__ ob2,
    float* __restrict__ e_atom,
    const int* __restrict__ rows, const int* __restrict__ cntp)
{
    __shared__ float As[32][36];
    __shared__ float Ws[32][128];
    __shared__ float Tl[32][132];
    __shared__ int rlist[32];

    const int tid = threadIdx.x;
    const int cnt = *cntp;
    const int r0 = (tid >> 4) * 2;
    const int c0 = (tid & 15) * 4;

    for (int tile = blockIdx.x; tile * 32 < cnt; tile += gridDim.x) {
        __syncthreads();
        if (tid < 32) {
            int idx = tile * 32 + tid;
            rlist[tid] = (idx < cnt) ? rows[idx] : -1;
        }
        __syncthreads();

        // phase A: T = tanh(agg @ l2w + l2b)
        float acc[2][8];
        #pragma unroll
        for (int j = 0; j < 2; ++j)
            #pragma unroll
            for (int c = 0; c < 8; ++c) acc[j][c] = 0.f;

        for (int kc = 0; kc < H; kc += 32) {
            {
                int lr = tid >> 3;
                int kk = (tid & 7) * 4;
                int r = rlist[lr];
                float4 v = make_float4(0.f, 0.f, 0.f, 0.f);
                if (r >= 0) v = *(const float4*)(agg + (size_t)r * H + kc + kk);
                *(float4*)&As[lr][kk] = v;
            }
            {
                int wr = tid >> 5;
                int wc = (tid & 31) * 4;
                #pragma unroll
                for (int p = 0; p < 4; ++p) {
                    int row = wr + p * 8;
                    *(float4*)&Ws[row][wc] = *(const float4*)(l2w + (size_t)(kc + row) * H + wc);
                }
            }
            __syncthreads();
            #pragma unroll
            for (int k = 0; k < 32; k += 4) {
                float a_[2][4];
                #pragma unroll
                for (int j = 0; j < 2; ++j)
                    *(float4*)a_[j] = *(const float4*)&As[r0 + j][k];
                #pragma unroll
                for (int kk = 0; kk < 4; ++kk) {
                    float4 wlo = *(const float4*)&Ws[k + kk][c0];
                    float4 whi = *(const float4*)&Ws[k + kk][c0 + 64];
                    float w_[8] = {wlo.x, wlo.y, wlo.z, wlo.w, whi.x, whi.y, whi.z, whi.w};
                    #pragma unroll
                    for (int j = 0; j < 2; ++j)
                        #pragma unroll
                        for (int c = 0; c < 8; ++c)
                            acc[j][c] = fmaf(a_[j][kk], w_[c], acc[j][c]);
                }
            }
            __syncthreads();
        }
        #pragma unroll
        for (int j = 0; j < 2; ++j) {
            float4 lo, hi;
            lo.x = tanhf(acc[j][0] + l2b[c0]);      lo.y = tanhf(acc[j][1] + l2b[c0 + 1]);
            lo.z = tanhf(acc[j][2] + l2b[c0 + 2]);  lo.w = tanhf(acc[j][3] + l2b[c0 + 3]);
            hi.x = tanhf(acc[j][4] + l2b[c0 + 64]); hi.y = tanhf(acc[j][5] + l2b[c0 + 65]);
            hi.z = tanhf(acc[j][6] + l2b[c0 + 66]); hi.w = tanhf(acc[j][7] + l2b[c0 + 67]);
            *(float4*)&Tl[r0 + j][c0] = lo;
            *(float4*)&Tl[r0 + j][c0 + 64] = hi;
        }

        // phase B: Xf = x[r] + T @ bw + bb  (kept in Tl)
        float acc2[2][8];
        #pragma unroll
        for (int j = 0; j < 2; ++j)
            #pragma unroll
            for (int c = 0; c < 8; ++c) acc2[j][c] = 0.f;

        for (int kc = 0; kc < H; kc += 32) {
            __syncthreads();
            {
                int wr = tid >> 5;
                int wc = (tid & 31) * 4;
                #pragma unroll
                for (int p = 0; p < 4; ++p) {
                    int row = wr + p * 8;
                    *(float4*)&Ws[row][wc] = *(const float4*)(bw + (size_t)(kc + row) * H + wc);
                }
            }
            __syncthreads();
            #pragma unroll
            for (int k = 0; k < 32; k += 4) {
                float a_[2][4];
                #pragma unroll
                for (int j = 0; j < 2; ++j)
                    *(float4*)a_[j] = *(const float4*)&Tl[r0 + j][kc + k];
                #pragma unroll
                for (int kk = 0; kk < 4; ++kk) {
                    float4 wlo = *(const float4*)&Ws[k + kk][c0];
                    float4 whi = *(const float4*)&Ws[k + kk][c0 + 64];
                    float w_[8] = {wlo.x, wlo.y, wlo.z, wlo.w, whi.x, whi.y, whi.z, whi.w};
                    #pragma unroll
                    for (int j = 0; j < 2; ++j)
                        #pragma unroll
                        for (int c = 0; c < 8; ++c)
                            acc2[j][c] = fmaf(a_[j][kk], w_[c], acc2[j][c]);
                }
            }
        }
        __syncthreads();   // all phase-B reads of Tl done before overwrite
        #pragma unroll
        for (int j = 0; j < 2; ++j) {
            int r = rlist[r0 + j];
            #pragma unroll
            for (int hh = 0; hh < 2; ++hh) {
                int cb = c0 + hh * 64;
                float4 xv = make_float4(0.f, 0.f, 0.f, 0.f);
                if (r >= 0) xv = *(const float4*)(x + (size_t)r * H + cb);
                xv.x += acc2[j][hh * 4 + 0] + bb[cb];
                xv.y += acc2[j][hh * 4 + 1] + bb[cb + 1];
                xv.z += acc2[j][hh * 4 + 2] + bb[cb + 2];
                xv.w += acc2[j][hh * 4 + 3] + bb[cb + 3];
                *(float4*)&Tl[r0 + j][cb] = xv;
            }
        }

        // phase C: y = tanh(Xf @ ow1 + ob1); e = y . ow2 + ob2
        float acc3[2][4];
        #pragma unroll
        for (int j = 0; j < 2; ++j)
            #pragma unroll
            for (int c = 0; c < 4; ++c) acc3[j][c] = 0.f;

        for (int kc = 0; kc < H; kc += 32) {
            __syncthreads();
            {
                int wr = tid >> 4;             // 0..15
                int wc = (tid & 15) * 4;       // 0..60
                #pragma unroll
                for (int p = 0; p < 2; ++p) {
                    int row = wr + p * 16;
                    *(float4*)&Ws[row][wc] = *(const float4*)(ow1 + (size_t)(kc + row) * 64 + wc);
                }
            }
            __syncthreads();
            #pragma unroll
            for (int k = 0; k < 32; ++k) {
                float a_[2];
                #pragma unroll
                for (int j = 0; j < 2; ++j) a_[j] = Tl[r0 + j][kc + k];
                float4 wv = *(const float4*)&Ws[k][c0];
                #pragma unroll
                for (int j = 0; j < 2; ++j) {
                    acc3[j][0] = fmaf(a_[j], wv.x, acc3[j][0]);
                    acc3[j][1] = fmaf(a_[j], wv.y, acc3[j][1]);
                    acc3[j][2] = fmaf(a_[j], wv.z, acc3[j][2]);
                    acc3[j][3] = fmaf(a_[j], wv.w, acc3[j][3]);
                }
            }
        }
        const float4 b1v = *(const float4*)(ob1 + c0);
        const float4 w2v = *(const float4*)(ow2 + c0);
        float ep[2];
        #pragma unroll
        for (int j = 0; j < 2; ++j) {
            float v0 = tanhf(acc3[j][0] + b1v.x);
            float v1 = tanhf(acc3[j][1] + b1v.y);
            float v2 = tanhf(acc3[j][2] + b1v.z);
            float v3 = tanhf(acc3[j][3] + b1v.w);
            ep[j] = v0 * w2v.x + v1 * w2v.y + v2 * w2v.z + v3 * w2v.w;
        }
        #pragma unroll
        for (int off = 1; off < 16; off <<= 1) {
            ep[0] += __shfl_xor(ep[0], off, 64);
            ep[1] += __shfl_xor(ep[1], off, 64);
        }
        if ((tid & 15) == 0) {
            const float b2v = ob2[0];
            #pragma unroll
            for (int j = 0; j < 2; ++j) {
                int r = rlist[r0 + j];
                if (r >= 0) e_atom[r] = ep[j] + b2v;
            }
        }
    }
}

// ---------------------------------------------------------------------------
// One block per graph: binary-search the sorted batch array for [start,end),
// sum dst atoms from e_atom and others from e_type. No atomics, no memset.
__global__ __launch_bounds__(256) void energy_graph_kernel(
    const int* __restrict__ batch, const int* __restrict__ atype,
    const int* __restrict__ is_dst, const float* __restrict__ e_atom,
    const float* __restrict__ e_type, float* __restrict__ energy, int Nn)
{
    const int g = blockIdx.x;
    int lo = 0, hi = Nn;
    while (lo < hi) { int m = (lo + hi) >> 1; if (batch[m] < g) lo = m + 1; else hi = m; }
    const int start = lo;
    hi = Nn;
    while (lo < hi) { int m = (lo + hi) >> 1; if (batch[m] < g + 1) lo = m + 1; else hi = m; }
    const int end = lo;

    float s = 0.0f;
    for (int n = start + (int)threadIdx.x; n < end; n += 256)
        s += is_dst[n] ? e_atom[n] : e_type[atype[n]];
    #pragma unroll
    for (int off = 32; off; off >>= 1) s += __shfl_xor(s, off, 64);
    __shared__ float wp[4];
    if ((threadIdx.x & 63) == 0) wp[threadIdx.x >> 6] = s;
    __syncthreads();
    if (threadIdx.x == 0) energy[g] = wp[0] + wp[1] + wp[2] + wp[3];
}

// ---------------------------------------------------------------------------
extern "C" void kernel_launch(void* const* d_in, const int* in_sizes, int n_in,
                              void* d_out, int out_size, void* d_ws, size_t ws_size,
                              hipStream_t stream)
{
    const int*   atype = (const int*)  d_in[0];
    const float* pos   = (const float*)d_in[1];
    const int*   ei    = (const int*)  d_in[2];
    const int*   batch = (const int*)  d_in[3];
    const float* emb   = (const float*)d_in[4];
    const float* fw1   = (const float*)d_in[5];
    const float* fb1   = (const float*)d_in[6];
    const float* fw2   = (const float*)d_in[7];
    const float* fb2   = (const float*)d_in[8];
    const float* lin1w = (const float*)d_in[9];
    const float* lin2w = (const float*)d_in[10];
    const float* lin2b = (const float*)d_in[11];
    const float* blkw  = (const float*)d_in[12];
    const float* blkb  = (const float*)d_in[13];
    const float* ow1   = (const float*)d_in[14];
    const float* ob1   = (const float*)d_in[15];
    const float* ow2   = (const float*)d_in[16];
    const float* ob2   = (const float*)d_in[17];

    const int Nn = in_sizes[0];
    const int E  = in_sizes[2] / 2;
    const int NT = in_sizes[4] / H;
    float* energy = (float*)d_out;

    // edge segmentation geometry
    const int eblocks = (E + 1023) / 1024;
    const int bps = (eblocks + SEG - 1) / SEG;
    const int CAP = bps * 1024;
    const int SEGCAP = SEG * CAP;

    // workspace layout (cnt + flags contiguous: zeroed by prep role)
    char* w = (char*)d_ws;
    int*   cnt  = (int*)w;           // [1]=src [2]=dst [3]=src&!dst ; [8..23]=seg
    int*   seg_cnt = cnt + 8;
    int*   is_src = cnt + 32;                           // N
    int*   is_dst = is_src + Nn;                        // N
    float* x    = (float*)(is_dst + Nn);                // N*H
    float* hbuf = x + (size_t)Nn * H;                   // N*H
    float* agg  = hbuf + (size_t)Nn * H;                // N*H
    int*   asrc = (int*)(agg + (size_t)Nn * H);         // SEGCAP
    int*   adst = asrc + SEGCAP;                        // SEGCAP
    float* ad   = (float*)(adst + SEGCAP);              // SEGCAP
    int*   src_list = (int*)(ad + SEGCAP);              // N
    int*   dst_list = src_list + Nn;                    // N
    int*   sn_list  = dst_list + Nn;                    // N
    float* cvec = (float*)(sn_list + Nn);               // 2*H
    float* tab  = cvec + 2 * H;                         // 2*(QT+1)*H
    float* e_type = tab + 2 * (size_t)(QT + 1) * H;     // 128
    float* e_atom = e_type + 128;                       // N
    float4* pos4 = (float4*)(e_atom + Nn);              // N

    // prep roles
    const int zquads = (128 + 2 * Nn * 4) / 16;         // cnt block + flags, int4s
    const int ZFB = (zquads + 255) / 256;
    const int PB  = (Nn + 255) / 256;
    const int FB  = (2 * (QT + 1) + 2 + 3) / 4;
    const int TB  = (NT + 3) / 4;

    prep_kernel<<<ZFB + PB + FB + TB, 256, 0, stream>>>(
        pos, pos4, Nn, (int4*)cnt, zquads,
        fw1, fb1, fw2, fb2, lin2b, blkw, blkb, emb,
        ow1, ob1, ow2, ob2, tab, cvec, e_type, NT, ZFB, PB, FB);

    edge_prep_kernel<<<eblocks, 256, 0, stream>>>(
        pos4, ei, E, CAP, seg_cnt, asrc, adst, ad, is_src, is_dst);
    compact_atoms_kernel<<<(Nn + 255) / 256, 256, 0, stream>>>(
        is_src, is_dst, Nn, cnt, src_list, dst_list, sn_list);

    // ---- interaction block 0 (x comes from emb[atype]) ----
    gemm_rows_zero_kernel<<<GB + ZB, 256, 0, stream>>>(
        nullptr, atype, emb, lin1w, hbuf, src_list, cnt + 1,
        agg, dst_list, cnt + 2);
    edge_scatter_kernel<<<1024, 256, 0, stream>>>(
        seg_cnt, asrc, adst, ad, tab, hbuf, agg, CAP);
    update_x0_kernel<<<UB + AB, 256, 0, stream>>>(
        agg, lin2w, lin2b, blkw, blkb, x, emb, atype,
        dst_list, cnt + 2, sn_list, cnt + 3, cvec);

    // ---- interaction block 1 (x materialized for src/dst rows) ----
    gemm_rows_zero_kernel<<<GB + ZB, 256, 0, stream>>>(
        x, nullptr, nullptr, lin1w + (size_t)H * H, hbuf, src_list, cnt + 1,
        agg, dst_list, cnt + 2);
    edge_scatter_kernel<<<1024, 256, 0, stream>>>(
        seg_cnt, asrc, adst, ad, tab + (size_t)(QT + 1) * H, hbuf, agg, CAP);
    update_e_kernel<<<512, 256, 0, stream>>>(
        agg, lin2w + (size_t)H * H, lin2b + H, blkw + (size_t)H * H, blkb + H,
        x, ow1, ob1, ow2, ob2, e_atom, dst_list, cnt + 2);

    // ---- per-graph energy ----
    energy_graph_kernel<<<out_size, 256, 0, stream>>>(
        batch, atype, is_dst, e_atom, e_type, energy, Nn);
}

// Round 10
// 223.152 us; speedup vs baseline: 1.5946x; 1.0554x over previous
//
#include <hip/hip_runtime.h>
#include <hip/hip_bf16.h>
#include <math.h>

#define H 128
#define RBF 50
#define CUTF 5.0f
#define PIF 3.14159265358979323846f
#define QT 1024                       // filter table intervals (QT+1 knots)
#define SEG 16                        // edge-compaction segments

// ---------------------------------------------------------------------------
// Prep mega-kernel, role-split by block ranges:
//  [0,ZFB)    zero counters + is_src/is_dst flags
//  +PB        pos4[n] = {x,y,z,0}
//  +FB        filter table (2*(QT+1) waves) + cvec (2 waves)
//  +TB        e_type[t] = head(emb[t] + cvec0 + cvec1)
//  +H0B       htype0[t] = emb[t] @ lin1w0
//  +H1B       htype1[t] = (emb[t] + cvec0) @ lin1w1   (cvec0 recomputed inline)
__global__ __launch_bounds__(256) void prep_kernel(
    const float* __restrict__ pos, float4* __restrict__ pos4, int Nn,
    int4* __restrict__ zbase, int zquads,
    const float* __restrict__ fw1, const float* __restrict__ fb1,
    const float* __restrict__ fw2, const float* __restrict__ fb2,
    const float* __restrict__ lin1w, const float* __restrict__ lin2b,
    const float* __restrict__ blkw, const float* __restrict__ blkb,
    const float* __restrict__ emb,
    const float* __restrict__ ow1, const float* __restrict__ ob1,
    const float* __restrict__ ow2, const float* __restrict__ ob2,
    float* __restrict__ tab, float* __restrict__ cvec,
    float* __restrict__ e_type, float* __restrict__ htype0,
    float* __restrict__ htype1, int NT,
    int ZFB, int PB, int FB, int TB, int H0B)
{
    int b = blockIdx.x;
    const int tid = threadIdx.x;
    const int lane = tid & 63;

    if (b < ZFB) {
        int i = b * 256 + tid;
        if (i < zquads) zbase[i] = make_int4(0, 0, 0, 0);
        return;
    }
    b -= ZFB;
    if (b < PB) {
        int n = b * 256 + tid;
        if (n < Nn)
            pos4[n] = make_float4(pos[3 * n], pos[3 * n + 1], pos[3 * n + 2], 0.0f);
        return;
    }
    b -= PB;
    const int h0 = lane, h1 = lane + 64;
    if (b < FB) {
        const int wid = b * 4 + (tid >> 6);
        const int ntab = 2 * (QT + 1);
        if (wid >= ntab + 2) return;
        if (wid >= ntab) {
            const int blk = wid - ntab;
            const float* bwp = blkw + (size_t)blk * H * H;
            float t0 = tanhf(lin2b[blk * H + h0]);
            float t1 = tanhf(lin2b[blk * H + h1]);
            float a0 = blkb[blk * H + h0], a1 = blkb[blk * H + h1];
            #pragma unroll 8
            for (int k = 0; k < 64; ++k) {
                float bb2 = __shfl(t0, k, 64);
                a0 = fmaf(bb2, bwp[k * H + h0], a0);
                a1 = fmaf(bb2, bwp[k * H + h1], a1);
            }
            #pragma unroll 8
            for (int k = 0; k < 64; ++k) {
                float bb2 = __shfl(t1, k, 64);
                a0 = fmaf(bb2, bwp[(64 + k) * H + h0], a0);
                a1 = fmaf(bb2, bwp[(64 + k) * H + h1], a1);
            }
            cvec[blk * H + h0] = a0;
            cvec[blk * H + h1] = a1;
            return;
        }
        const int blk = wid / (QT + 1);
        const int q = wid - blk * (QT + 1);
        const float d = (float)q * (CUTF / (float)QT);
        const float* f1 = fw1 + (size_t)blk * RBF * H;
        const float* f2 = fw2 + (size_t)blk * H * H;
        const float step  = CUTF / 49.0f;
        const float coeff = -0.5f / (step * step);
        float cenv = (d < CUTF) ? 0.5f * (cosf(d * (PIF / CUTF)) + 1.0f) : 0.0f;

        float t0 = fb1[blk * H + h0], t1 = fb1[blk * H + h1];
        #pragma unroll
        for (int r = 0; r < RBF; ++r) {
            float u = d - (float)r * step;
            float rb = expf(coeff * u * u);
            t0 = fmaf(rb, f1[r * H + h0], t0);
            t1 = fmaf(rb, f1[r * H + h1], t1);
        }
        t0 = tanhf(t0); t1 = tanhf(t1);
        float w0 = fb2[blk * H + h0], w1v = fb2[blk * H + h1];
        #pragma unroll 8
        for (int k = 0; k < 64; ++k) {
            float bb2 = __shfl(t0, k, 64);
            w0  = fmaf(bb2, f2[k * H + h0], w0);
            w1v = fmaf(bb2, f2[k * H + h1], w1v);
        }
        #pragma unroll 8
        for (int k = 0; k < 64; ++k) {
            float bb2 = __shfl(t1, k, 64);
            w0  = fmaf(bb2, f2[(64 + k) * H + h0], w0);
            w1v = fmaf(bb2, f2[(64 + k) * H + h1], w1v);
        }
        float* row = tab + ((size_t)blk * (QT + 1) + q) * H;
        row[h0] = w0 * cenv;
        row[h1] = w1v * cenv;
        return;
    }
    b -= FB;
    if (b < TB) {
        // e_type role
        const int ty = b * 4 + (tid >> 6);
        if (ty >= NT) return;
        float xt0 = emb[(size_t)ty * H + h0];
        float xt1 = emb[(size_t)ty * H + h1];
        #pragma unroll
        for (int blk = 0; blk < 2; ++blk) {
            const float* bwp = blkw + (size_t)blk * H * H;
            float t0 = tanhf(lin2b[blk * H + h0]);
            float t1 = tanhf(lin2b[blk * H + h1]);
            float a0 = blkb[blk * H + h0], a1 = blkb[blk * H + h1];
            #pragma unroll 8
            for (int k = 0; k < 64; ++k) {
                float bb2 = __shfl(t0, k, 64);
                a0 = fmaf(bb2, bwp[k * H + h0], a0);
                a1 = fmaf(bb2, bwp[k * H + h1], a1);
            }
            #pragma unroll 8
            for (int k = 0; k < 64; ++k) {
                float bb2 = __shfl(t1, k, 64);
                a0 = fmaf(bb2, bwp[(64 + k) * H + h0], a0);
                a1 = fmaf(bb2, bwp[(64 + k) * H + h1], a1);
            }
            xt0 += a0; xt1 += a1;
        }
        float y = ob1[lane];
        #pragma unroll 8
        for (int k = 0; k < 64; ++k) {
            float bb2 = __shfl(xt0, k, 64);
            y = fmaf(bb2, ow1[k * 64 + lane], y);
        }
        #pragma unroll 8
        for (int k = 0; k < 64; ++k) {
            float bb2 = __shfl(xt1, k, 64);
            y = fmaf(bb2, ow1[(64 + k) * 64 + lane], y);
        }
        y = tanhf(y) * ow2[lane];
        #pragma unroll
        for (int off = 32; off; off >>= 1) y += __shfl_xor(y, off, 64);
        if (lane == 0) e_type[ty] = y + ob2[0];
        return;
    }
    b -= TB;
    if (b < H0B) {
        // htype0[t] = emb[t] @ lin1w0
        const int ty = b * 4 + (tid >> 6);
        if (ty >= NT) return;
        float x0 = emb[(size_t)ty * H + h0];
        float x1 = emb[(size_t)ty * H + h1];
        float a0 = 0.f, a1 = 0.f;
        #pragma unroll 8
        for (int k = 0; k < 64; ++k) {
            float bb2 = __shfl(x0, k, 64);
            a0 = fmaf(bb2, lin1w[k * H + h0], a0);
            a1 = fmaf(bb2, lin1w[k * H + h1], a1);
        }
        #pragma unroll 8
        for (int k = 0; k < 64; ++k) {
            float bb2 = __shfl(x1, k, 64);
            a0 = fmaf(bb2, lin1w[(64 + k) * H + h0], a0);
            a1 = fmaf(bb2, lin1w[(64 + k) * H + h1], a1);
        }
        htype0[(size_t)ty * H + h0] = a0;
        htype0[(size_t)ty * H + h1] = a1;
        return;
    }
    b -= H0B;
    {
        // htype1[t] = (emb[t] + cvec0) @ lin1w1 ; cvec0 recomputed inline
        const int ty = b * 4 + (tid >> 6);
        if (ty >= NT) return;
        const float* bwp = blkw;           // block 0
        float t0 = tanhf(lin2b[h0]);
        float t1 = tanhf(lin2b[h1]);
        float c0 = blkb[h0], c1 = blkb[h1];
        #pragma unroll 8
        for (int k = 0; k < 64; ++k) {
            float bb2 = __shfl(t0, k, 64);
            c0 = fmaf(bb2, bwp[k * H + h0], c0);
            c1 = fmaf(bb2, bwp[k * H + h1], c1);
        }
        #pragma unroll 8
        for (int k = 0; k < 64; ++k) {
            float bb2 = __shfl(t1, k, 64);
            c0 = fmaf(bb2, bwp[(64 + k) * H + h0], c0);
            c1 = fmaf(bb2, bwp[(64 + k) * H + h1], c1);
        }
        float x0 = emb[(size_t)ty * H + h0] + c0;
        float x1 = emb[(size_t)ty * H + h1] + c1;
        const float* l1 = lin1w + (size_t)H * H;   // block 1
        float a0 = 0.f, a1 = 0.f;
        #pragma unroll 8
        for (int k = 0; k < 64; ++k) {
            float bb2 = __shfl(x0, k, 64);
            a0 = fmaf(bb2, l1[k * H + h0], a0);
            a1 = fmaf(bb2, l1[k * H + h1], a1);
        }
        #pragma unroll 8
        for (int k = 0; k < 64; ++k) {
            float bb2 = __shfl(x1, k, 64);
            a0 = fmaf(bb2, l1[(64 + k) * H + h0], a0);
            a1 = fmaf(bb2, l1[(64 + k) * H + h1], a1);
        }
        htype1[(size_t)ty * H + h0] = a0;
        htype1[(size_t)ty * H + h1] = a1;
    }
}

// ---------------------------------------------------------------------------
// Edge compaction, 4 edges/thread, block-aggregated atomics into SEG counters.
// Stores src, dst, d, and src atom type per active edge.
__global__ __launch_bounds__(256) void edge_prep_kernel(
    const float4* __restrict__ pos4, const int* __restrict__ ei,
    const int* __restrict__ atype, int E, int CAP,
    int* __restrict__ seg_cnt, int* __restrict__ asrc, int* __restrict__ adst,
    float* __restrict__ ad, int* __restrict__ asty,
    int* __restrict__ is_src, int* __restrict__ is_dst)
{
    __shared__ int wtot[4], wbase[4];
    const int tid = threadIdx.x;
    const int lane = tid & 63;
    const int wv = tid >> 6;
    const int gtid = blockIdx.x * 256 + tid;

    int s[4], t[4];
    float d[4];
    bool act[4] = {false, false, false, false};

    const int e0 = gtid * 4;
    if (e0 + 3 < E && (E & 3) == 0) {
        const int4 sv = *(const int4*)(ei + e0);
        const int4 tv = *(const int4*)(ei + E + e0);
        s[0] = sv.x; s[1] = sv.y; s[2] = sv.z; s[3] = sv.w;
        t[0] = tv.x; t[1] = tv.y; t[2] = tv.z; t[3] = tv.w;
        #pragma unroll
        for (int j = 0; j < 4; ++j) {
            float4 ps = pos4[s[j]], pt = pos4[t[j]];
            float dx = ps.x - pt.x, dy = ps.y - pt.y, dz = ps.z - pt.z;
            d[j] = sqrtf(dx * dx + dy * dy + dz * dz + 1e-12f);
            act[j] = (d[j] < CUTF);
        }
    } else if (e0 < E) {
        #pragma unroll
        for (int j = 0; j < 4; ++j) {
            int e = e0 + j;
            if (e < E) {
                s[j] = ei[e]; t[j] = ei[E + e];
                float4 ps = pos4[s[j]], pt = pos4[t[j]];
                float dx = ps.x - pt.x, dy = ps.y - pt.y, dz = ps.z - pt.z;
                d[j] = sqrtf(dx * dx + dy * dy + dz * dz + 1e-12f);
                act[j] = (d[j] < CUTF);
            }
        }
    }

    unsigned long long b[4];
    int mytot = 0;
    #pragma unroll
    for (int j = 0; j < 4; ++j) {
        b[j] = __ballot(act[j]);
        mytot += (int)__popcll(b[j]);
    }
    if (lane == 0) wtot[wv] = mytot;
    __syncthreads();
    if (tid == 0) {
        int t0 = wtot[0], t1 = wtot[1], t2 = wtot[2], t3 = wtot[3];
        int tot = t0 + t1 + t2 + t3;
        int base = 0;
        if (tot) base = atomicAdd(&seg_cnt[blockIdx.x & (SEG - 1)], tot);
        wbase[0] = base; wbase[1] = base + t0;
        wbase[2] = base + t0 + t1; wbase[3] = base + t0 + t1 + t2;
    }
    __syncthreads();

    int run = wbase[wv];
    const int segoff = (int)(blockIdx.x & (SEG - 1)) * CAP;
    const unsigned long long ltm = ((unsigned long long)1 << lane) - 1;
    #pragma unroll
    for (int j = 0; j < 4; ++j) {
        if (act[j]) {
            int p = segoff + run + (int)__popcll(b[j] & ltm);
            asrc[p] = s[j]; adst[p] = t[j]; ad[p] = d[j];
            asty[p] = atype[s[j]];
            is_src[s[j]] = 1; is_dst[t[j]] = 1;
        }
        run += (int)__popcll(b[j]);
    }
}

// ---------------------------------------------------------------------------
// Atom lists: [1]=dst, [2]=src&&dst. Also zeroes agg rows for dst atoms.
__global__ __launch_bounds__(256) void compact_atoms_kernel(
    const int* __restrict__ is_src, const int* __restrict__ is_dst, int Nn,
    int* __restrict__ cnt4,
    int* __restrict__ dst_list, int* __restrict__ sd_list,
    float* __restrict__ agg)
{
    __shared__ int wtot[2][4], wbase[2][4];
    const int tid = threadIdx.x;
    const int lane = tid & 63;
    const int wv = tid >> 6;
    int n = blockIdx.x * 256 + tid;
    bool v[2] = {false, false};
    if (n < Nn) {
        bool vd = is_dst[n] != 0;
        v[0] = vd;
        v[1] = vd && (is_src[n] != 0);
    }
    unsigned long long b[2];
    #pragma unroll
    for (int l = 0; l < 2; ++l) {
        b[l] = __ballot(v[l]);
        if (lane == 0) wtot[l][wv] = (int)__popcll(b[l]);
    }
    __syncthreads();
    if (tid == 0) {
        #pragma unroll
        for (int l = 0; l < 2; ++l) {
            int t0 = wtot[l][0], t1 = wtot[l][1], t2 = wtot[l][2], t3 = wtot[l][3];
            int tot = t0 + t1 + t2 + t3;
            int base = 0;
            if (tot) base = atomicAdd(cnt4 + 1 + l, tot);
            wbase[l][0] = base; wbase[l][1] = base + t0;
            wbase[l][2] = base + t0 + t1; wbase[l][3] = base + t0 + t1 + t2;
        }
    }
    __syncthreads();
    const unsigned long long ltm = ((unsigned long long)1 << lane) - 1;
    if (v[0]) dst_list[wbase[0][wv] + (int)__popcll(b[0] & ltm)] = n;
    if (v[1]) sd_list[wbase[1][wv] + (int)__popcll(b[1] & ltm)] = n;
    // zero agg rows for dst atoms (pass-1 zeroing)
    if (v[0]) {
        float4 z = make_float4(0.f, 0.f, 0.f, 0.f);
        float4* row = (float4*)(agg + (size_t)n * H);
        #pragma unroll
        for (int c = 0; c < 32; ++c) row[c] = z;
    }
}

// ---------------------------------------------------------------------------
// Scatter pass 0: h[src] comes from htype0[asty] (51 KB L2 table).
__global__ __launch_bounds__(256) void edge_scatter0_kernel(
    const int* __restrict__ seg_cnt,
    const int* __restrict__ adst, const float* __restrict__ ad,
    const int* __restrict__ asty, const float* __restrict__ tab,
    const float* __restrict__ htype0, float* __restrict__ agg, int CAP)
{
    __shared__ int sbase[SEG + 1];
    const int tid = threadIdx.x;
    if (tid == 0) {
        int run = 0;
        #pragma unroll
        for (int s2 = 0; s2 < SEG; ++s2) { sbase[s2] = run; run += seg_cnt[s2]; }
        sbase[SEG] = run;
    }
    __syncthreads();

    const int lane = tid & 63;
    const int wid = (blockIdx.x * blockDim.x + tid) >> 6;
    const int nw  = (gridDim.x * blockDim.x) >> 6;
    const int total = sbase[SEG];
    const float scale = (float)QT / CUTF;

    for (int i = wid; i < total; i += nw) {
        int seg = 0;
        #pragma unroll
        for (int s2 = 1; s2 < SEG; ++s2) seg += (i >= sbase[s2]) ? 1 : 0;
        int slot = seg * CAP + (i - sbase[seg]);

        int t = adst[slot];
        int ty = asty[slot];
        float p = ad[slot] * scale;
        int i0 = (int)p;
        if (i0 > QT - 1) i0 = QT - 1;
        float f = p - (float)i0;
        const float* r0 = tab + (size_t)i0 * H;
        float wl = fmaf(f, r0[H + lane] - r0[lane], r0[lane]);
        float wh = fmaf(f, r0[H + 64 + lane] - r0[64 + lane], r0[64 + lane]);
        const float* hr = htype0 + (size_t)ty * H;
        atomicAdd(agg + (size_t)t * H + lane, hr[lane] * wl);
        atomicAdd(agg + (size_t)t * H + 64 + lane, hr[64 + lane] * wh);
    }
}

// ---------------------------------------------------------------------------
// Scatter pass 1: h[src] = hbuf[s] if is_dst[s] (individual) else htype1[ty].
__global__ __launch_bounds__(256) void edge_scatter1_kernel(
    const int* __restrict__ seg_cnt,
    const int* __restrict__ asrc, const int* __restrict__ adst,
    const float* __restrict__ ad, const int* __restrict__ asty,
    const int* __restrict__ is_dst, const float* __restrict__ tab,
    const float* __restrict__ hbuf, const float* __restrict__ htype1,
    float* __restrict__ agg, int CAP)
{
    __shared__ int sbase[SEG + 1];
    const int tid = threadIdx.x;
    if (tid == 0) {
        int run = 0;
        #pragma unroll
        for (int s2 = 0; s2 < SEG; ++s2) { sbase[s2] = run; run += seg_cnt[s2]; }
        sbase[SEG] = run;
    }
    __syncthreads();

    const int lane = tid & 63;
    const int wid = (blockIdx.x * blockDim.x + tid) >> 6;
    const int nw  = (gridDim.x * blockDim.x) >> 6;
    const int total = sbase[SEG];
    const float scale = (float)QT / CUTF;

    for (int i = wid; i < total; i += nw) {
        int seg = 0;
        #pragma unroll
        for (int s2 = 1; s2 < SEG; ++s2) seg += (i >= sbase[s2]) ? 1 : 0;
        int slot = seg * CAP + (i - sbase[seg]);

        int s = asrc[slot];
        int t = adst[slot];
        float p = ad[slot] * scale;
        int i0 = (int)p;
        if (i0 > QT - 1) i0 = QT - 1;
        float f = p - (float)i0;
        const float* r0 = tab + (size_t)i0 * H;
        float wl = fmaf(f, r0[H + lane] - r0[lane], r0[lane]);
        float wh = fmaf(f, r0[H + 64 + lane] - r0[64 + lane], r0[64 + lane]);
        // wave-uniform branch: s identical across lanes
        const float* hr = is_dst[s] ? (hbuf + (size_t)s * H)
                                    : (htype1 + (size_t)asty[slot] * H);
        atomicAdd(agg + (size_t)t * H + lane, hr[lane] * wl);
        atomicAdd(agg + (size_t)t * H + 64 + lane, hr[64 + lane] * wh);
    }
}

// ---------------------------------------------------------------------------
// Gathered GEMM over sd rows: hbuf[r] = x[r] @ W  (32-row tiles)
__global__ __launch_bounds__(256) void gemm_sd_kernel(
    const float* __restrict__ A, const float* __restrict__ W,
    float* __restrict__ C,
    const int* __restrict__ rows, const int* __restrict__ cntp)
{
    __shared__ float As[32][36];
    __shared__ float Ws[32][128];
    __shared__ int rlist[32];

    const int tid = threadIdx.x;
    const int cnt = *cntp;
    const int r0 = (tid >> 4) * 2;
    const int c0 = (tid & 15) * 4;

    for (int tile = blockIdx.x; tile * 32 < cnt; tile += gridDim.x) {
        __syncthreads();
        if (tid < 32) {
            int idx = tile * 32 + tid;
            rlist[tid] = (idx < cnt) ? rows[idx] : -1;
        }
        __syncthreads();

        float acc[2][8];
        #pragma unroll
        for (int j = 0; j < 2; ++j)
            #pragma unroll
            for (int c = 0; c < 8; ++c) acc[j][c] = 0.f;

        for (int kc = 0; kc < H; kc += 32) {
            {
                int lr = tid >> 3;
                int kk = (tid & 7) * 4;
                int r = rlist[lr];
                float4 v = make_float4(0.f, 0.f, 0.f, 0.f);
                if (r >= 0) v = *(const float4*)(A + (size_t)r * H + kc + kk);
                *(float4*)&As[lr][kk] = v;
            }
            {
                int wr = tid >> 5;
                int wc = (tid & 31) * 4;
                #pragma unroll
                for (int p = 0; p < 4; ++p) {
                    int row = wr + p * 8;
                    *(float4*)&Ws[row][wc] = *(const float4*)(W + (size_t)(kc + row) * H + wc);
                }
            }
            __syncthreads();
            #pragma unroll
            for (int k = 0; k < 32; k += 4) {
                float a_[2][4];
                #pragma unroll
                for (int j = 0; j < 2; ++j)
                    *(float4*)a_[j] = *(const float4*)&As[r0 + j][k];
                #pragma unroll
                for (int kk = 0; kk < 4; ++kk) {
                    float4 wlo = *(const float4*)&Ws[k + kk][c0];
                    float4 whi = *(const float4*)&Ws[k + kk][c0 + 64];
                    float w_[8] = {wlo.x, wlo.y, wlo.z, wlo.w, whi.x, whi.y, whi.z, whi.w};
                    #pragma unroll
                    for (int j = 0; j < 2; ++j)
                        #pragma unroll
                        for (int c = 0; c < 8; ++c)
                            acc[j][c] = fmaf(a_[j][kk], w_[c], acc[j][c]);
                }
            }
            __syncthreads();
        }
        #pragma unroll
        for (int j = 0; j < 2; ++j) {
            int r = rlist[r0 + j];
            if (r < 0) continue;
            #pragma unroll
            for (int hh = 0; hh < 2; ++hh) {
                int cb = c0 + hh * 64;
                *(float4*)(C + (size_t)r * H + cb) = make_float4(
                    acc[j][hh * 4 + 0], acc[j][hh * 4 + 1],
                    acc[j][hh * 4 + 2], acc[j][hh * 4 + 3]);
            }
        }
    }
}

// ---------------------------------------------------------------------------
// Block-0 update over dst rows: x[r] = emb[atype[r]] + tanh(agg@l2w+l2b)@bw+bb.
// Also re-zeroes agg rows for pass 2 (after last read).
__global__ __launch_bounds__(256) void update_x0_kernel(
    float* __restrict__ agg, const float* __restrict__ l2w,
    const float* __restrict__ l2b, const float* __restrict__ bw,
    const float* __restrict__ bb, float* __restrict__ x,
    const float* __restrict__ emb, const int* __restrict__ atype,
    const int* __restrict__ rows, const int* __restrict__ cntp)
{
    __shared__ float As[32][36];
    __shared__ float Ws[32][128];
    __shared__ float Tl[32][132];
    __shared__ int rlist[32], tlist[32];

    const int tid = threadIdx.x;
    const int cnt = *cntp;
    const int r0 = (tid >> 4) * 2;
    const int c0 = (tid & 15) * 4;

    for (int tile = blockIdx.x; tile * 32 < cnt; tile += gridDim.x) {
        __syncthreads();
        if (tid < 32) {
            int idx = tile * 32 + tid;
            int r = (idx < cnt) ? rows[idx] : -1;
            rlist[tid] = r;
            tlist[tid] = (r >= 0) ? atype[r] : 0;
        }
        __syncthreads();

        // phase A: T = tanh(agg @ l2w + l2b)
        float acc[2][8];
        #pragma unroll
        for (int j = 0; j < 2; ++j)
            #pragma unroll
            for (int c = 0; c < 8; ++c) acc[j][c] = 0.f;

        for (int kc = 0; kc < H; kc += 32) {
            {
                int lr = tid >> 3;
                int kk = (tid & 7) * 4;
                int r = rlist[lr];
                float4 v = make_float4(0.f, 0.f, 0.f, 0.f);
                if (r >= 0) v = *(const float4*)(agg + (size_t)r * H + kc + kk);
                *(float4*)&As[lr][kk] = v;
            }
            {
                int wr = tid >> 5;
                int wc = (tid & 31) * 4;
                #pragma unroll
                for (int p = 0; p < 4; ++p) {
                    int row = wr + p * 8;
                    *(float4*)&Ws[row][wc] = *(const float4*)(l2w + (size_t)(kc + row) * H + wc);
                }
            }
            __syncthreads();
            #pragma unroll
            for (int k = 0; k < 32; k += 4) {
                float a_[2][4];
                #pragma unroll
                for (int j = 0; j < 2; ++j)
                    *(float4*)a_[j] = *(const float4*)&As[r0 + j][k];
                #pragma unroll
                for (int kk = 0; kk < 4; ++kk) {
                    float4 wlo = *(const float4*)&Ws[k + kk][c0];
                    float4 whi = *(const float4*)&Ws[k + kk][c0 + 64];
                    float w_[8] = {wlo.x, wlo.y, wlo.z, wlo.w, whi.x, whi.y, whi.z, whi.w};
                    #pragma unroll
                    for (int j = 0; j < 2; ++j)
                        #pragma unroll
                        for (int c = 0; c < 8; ++c)
                            acc[j][c] = fmaf(a_[j][kk], w_[c], acc[j][c]);
                }
            }
            __syncthreads();
        }
        // re-zero agg rows of this tile (all reads complete)
        {
            float4 z = make_float4(0.f, 0.f, 0.f, 0.f);
            for (int idx = tid; idx < 32 * 32; idx += 256) {
                int row = idx >> 5, c = (idx & 31) << 2;
                int r = rlist[row];
                if (r >= 0) *(float4*)(agg + (size_t)r * H + c) = z;
            }
        }
        #pragma unroll
        for (int j = 0; j < 2; ++j) {
            float4 lo, hi;
            lo.x = tanhf(acc[j][0] + l2b[c0]);      lo.y = tanhf(acc[j][1] + l2b[c0 + 1]);
            lo.z = tanhf(acc[j][2] + l2b[c0 + 2]);  lo.w = tanhf(acc[j][3] + l2b[c0 + 3]);
            hi.x = tanhf(acc[j][4] + l2b[c0 + 64]); hi.y = tanhf(acc[j][5] + l2b[c0 + 65]);
            hi.z = tanhf(acc[j][6] + l2b[c0 + 66]); hi.w = tanhf(acc[j][7] + l2b[c0 + 67]);
            *(float4*)&Tl[r0 + j][c0] = lo;
            *(float4*)&Tl[r0 + j][c0 + 64] = hi;
        }

        // phase B: x[r] = emb[ty] + T @ bw + bb
        float acc2[2][8];
        #pragma unroll
        for (int j = 0; j < 2; ++j)
            #pragma unroll
            for (int c = 0; c < 8; ++c) acc2[j][c] = 0.f;

        for (int kc = 0; kc < H; kc += 32) {
            __syncthreads();
            {
                int wr = tid >> 5;
                int wc = (tid & 31) * 4;
                #pragma unroll
                for (int p = 0; p < 4; ++p) {
                    int row = wr + p * 8;
                    *(float4*)&Ws[row][wc] = *(const float4*)(bw + (size_t)(kc + row) * H + wc);
                }
            }
            __syncthreads();
            #pragma unroll
            for (int k = 0; k < 32; k += 4) {
                float a_[2][4];
                #pragma unroll
                for (int j = 0; j < 2; ++j)
                    *(float4*)a_[j] = *(const float4*)&Tl[r0 + j][kc + k];
                #pragma unroll
                for (int kk = 0; kk < 4; ++kk) {
                    float4 wlo = *(const float4*)&Ws[k + kk][c0];
                    float4 whi = *(const float4*)&Ws[k + kk][c0 + 64];
                    float w_[8] = {wlo.x, wlo.y, wlo.z, wlo.w, whi.x, whi.y, whi.z, whi.w};
                    #pragma unroll
                    for (int j = 0; j < 2; ++j)
                        #pragma unroll
                        for (int c = 0; c < 8; ++c)
                            acc2[j][c] = fmaf(a_[j][kk], w_[c], acc2[j][c]);
                }
            }
        }
        #pragma unroll
        for (int j = 0; j < 2; ++j) {
            int r = rlist[r0 + j];
            if (r < 0) continue;
            int ty = tlist[r0 + j];
            #pragma unroll
            for (int hh = 0; hh < 2; ++hh) {
                int cb = c0 + hh * 64;
                float4 xv = *(const float4*)(emb + (size_t)ty * H + cb);
                xv.x += acc2[j][hh * 4 + 0] + bb[cb];
                xv.y += acc2[j][hh * 4 + 1] + bb[cb + 1];
                xv.z += acc2[j][hh * 4 + 2] + bb[cb + 2];
                xv.w += acc2[j][hh * 4 + 3] + bb[cb + 3];
                *(float4*)(x + (size_t)r * H + cb) = xv;
            }
        }
    }
}

// ---------------------------------------------------------------------------
// Block-1 update fused with output head: e_atom[r] for dst rows.
__global__ __launch_bounds__(256) void update_e_kernel(
    const float* __restrict__ agg, const float* __restrict__ l2w,
    const float* __restrict__ l2b, const float* __restrict__ bw,
    const float* __restrict__ bb, const float* __restrict__ x,
    const float* __restrict__ ow1, const float* __restrict__ ob1,
    const float* __restrict__ ow2, const float* __restrict__ ob2,
    float* __restrict__ e_atom,
    const int* __restrict__ rows, const int* __restrict__ cntp)
{
    __shared__ float As[32][36];
    __shared__ float Ws[32][128];
    __shared__ float Tl[32][132];
    __shared__ int rlist[32];

    const int tid = threadIdx.x;
    const int cnt = *cntp;
    const int r0 = (tid >> 4) * 2;
    const int c0 = (tid & 15) * 4;

    for (int tile = blockIdx.x; tile * 32 < cnt; tile += gridDim.x) {
        __syncthreads();
        if (tid < 32) {
            int idx = tile * 32 + tid;
            rlist[tid] = (idx < cnt) ? rows[idx] : -1;
        }
        __syncthreads();

        float acc[2][8];
        #pragma unroll
        for (int j = 0; j < 2; ++j)
            #pragma unroll
            for (int c = 0; c < 8; ++c) acc[j][c] = 0.f;

        for (int kc = 0; kc < H; kc += 32) {
            {
                int lr = tid >> 3;
                int kk = (tid & 7) * 4;
                int r = rlist[lr];
                float4 v = make_float4(0.f, 0.f, 0.f, 0.f);
                if (r >= 0) v = *(const float4*)(agg + (size_t)r * H + kc + kk);
                *(float4*)&As[lr][kk] = v;
            }
            {
                int wr = tid >> 5;
                int wc = (tid & 31) * 4;
                #pragma unroll
                for (int p = 0; p < 4; ++p) {
                    int row = wr + p * 8;
                    *(float4*)&Ws[row][wc] = *(const float4*)(l2w + (size_t)(kc + row) * H + wc);
                }
            }
            __syncthreads();
            #pragma unroll
            for (int k = 0; k < 32; k += 4) {
                float a_[2][4];
                #pragma unroll
                for (int j = 0; j < 2; ++j)
                    *(float4*)a_[j] = *(const float4*)&As[r0 + j][k];
                #pragma unroll
                for (int kk = 0; kk < 4; ++kk) {
                    float4 wlo = *(const float4*)&Ws[k + kk][c0];
                    float4 whi = *(const float4*)&Ws[k + kk][c0 + 64];
                    float w_[8] = {wlo.x, wlo.y, wlo.z, wlo.w, whi.x, whi.y, whi.z, whi.w};
                    #pragma unroll
                    for (int j = 0; j < 2; ++j)
                        #pragma unroll
                        for (int c = 0; c < 8; ++c)
                            acc[j][c] = fmaf(a_[j][kk], w_[c], acc[j][c]);
                }
            }
            __syncthreads();
        }
        #pragma unroll
        for (int j = 0; j < 2; ++j) {
            float4 lo, hi;
            lo.x = tanhf(acc[j][0] + l2b[c0]);      lo.y = tanhf(acc[j][1] + l2b[c0 + 1]);
            lo.z = tanhf(acc[j][2] + l2b[c0 + 2]);  lo.w = tanhf(acc[j][3] + l2b[c0 + 3]);
            hi.x = tanhf(acc[j][4] + l2b[c0 + 64]); hi.y = tanhf(acc[j][5] + l2b[c0 + 65]);
            hi.z = tanhf(acc[j][6] + l2b[c0 + 66]); hi.w = tanhf(acc[j][7] + l2b[c0 + 67]);
            *(float4*)&Tl[r0 + j][c0] = lo;
            *(float4*)&Tl[r0 + j][c0 + 64] = hi;
        }

        float acc2[2][8];
        #pragma unroll
        for (int j = 0; j < 2; ++j)
            #pragma unroll
            for (int c = 0; c < 8; ++c) acc2[j][c] = 0.f;

        for (int kc = 0; kc < H; kc += 32) {
            __syncthreads();
            {
                int wr = tid >> 5;
                int wc = (tid & 31) * 4;
                #pragma unroll
                for (int p = 0; p < 4; ++p) {
                    int row = wr + p * 8;
                    *(float4*)&Ws[row][wc] = *(const float4*)(bw + (size_t)(kc + row) * H + wc);
                }
            }
            __syncthreads();
            #pragma unroll
            for (int k = 0; k < 32; k += 4) {
                float a_[2][4];
                #pragma unroll
                for (int j = 0; j < 2; ++j)
                    *(float4*)a_[j] = *(const float4*)&Tl[r0 + j][kc + k];
                #pragma unroll
                for (int kk = 0; kk < 4; ++kk) {
                    float4 wlo = *(const float4*)&Ws[k + kk][c0];
                    float4 whi = *(const float4*)&Ws[k + kk][c0 + 64];
                    float w_[8] = {wlo.x, wlo.y, wlo.z, wlo.w, whi.x, whi.y, whi.z, whi.w};
                    #pragma unroll
                    for (int j = 0; j < 2; ++j)
                        #pragma unroll
                        for (int c = 0; c < 8; ++c)
                            acc2[j][c] = fmaf(a_[j][kk], w_[c], acc2[j][c]);
                }
            }
        }
        __syncthreads();
        #pragma unroll
        for (int j = 0; j < 2; ++j) {
            int r = rlist[r0 + j];
            #pragma unroll
            for (int hh = 0; hh < 2; ++hh) {
                int cb = c0 + hh * 64;
                float4 xv = make_float4(0.f, 0.f, 0.f, 0.f);
                if (r >= 0) xv = *(const float4*)(x + (size_t)r * H + cb);
                xv.x += acc2[j][hh * 4 + 0] + bb[cb];
                xv.y += acc2[j][hh * 4 + 1] + bb[cb + 1];
                xv.z += acc2[j][hh * 4 + 2] + bb[cb + 2];
                xv.w += acc2[j][hh * 4 + 3] + bb[cb + 3];
                *(float4*)&Tl[r0 + j][cb] = xv;
            }
        }

        float acc3[2][4];
        #pragma unroll
        for (int j = 0; j < 2; ++j)
            #pragma unroll
            for (int c = 0; c < 4; ++c) acc3[j][c] = 0.f;

        for (int kc = 0; kc < H; kc += 32) {
            __syncthreads();
            {
                int wr = tid >> 4;
                int wc = (tid & 15) * 4;
                #pragma unroll
                for (int p = 0; p < 2; ++p) {
                    int row = wr + p * 16;
                    *(float4*)&Ws[row][wc] = *(const float4*)(ow1 + (size_t)(kc + row) * 64 + wc);
                }
            }
            __syncthreads();
            #pragma unroll
            for (int k = 0; k < 32; ++k) {
                float a_[2];
                #pragma unroll
                for (int j = 0; j < 2; ++j) a_[j] = Tl[r0 + j][kc + k];
                float4 wv = *(const float4*)&Ws[k][c0];
                #pragma unroll
                for (int j = 0; j < 2; ++j) {
                    acc3[j][0] = fmaf(a_[j], wv.x, acc3[j][0]);
                    acc3[j][1] = fmaf(a_[j], wv.y, acc3[j][1]);
                    acc3[j][2] = fmaf(a_[j], wv.z, acc3[j][2]);
                    acc3[j][3] = fmaf(a_[j], wv.w, acc3[j][3]);
                }
            }
        }
        const float4 b1v = *(const float4*)(ob1 + c0);
        const float4 w2v = *(const float4*)(ow2 + c0);
        float ep[2];
        #pragma unroll
        for (int j = 0; j < 2; ++j) {
            float v0 = tanhf(acc3[j][0] + b1v.x);
            float v1 = tanhf(acc3[j][1] + b1v.y);
            float v2 = tanhf(acc3[j][2] + b1v.z);
            float v3 = tanhf(acc3[j][3] + b1v.w);
            ep[j] = v0 * w2v.x + v1 * w2v.y + v2 * w2v.z + v3 * w2v.w;
        }
        #pragma unroll
        for (int off = 1; off < 16; off <<= 1) {
            ep[0] += __shfl_xor(ep[0], off, 64);
            ep[1] += __shfl_xor(ep[1], off, 64);
        }
        if ((tid & 15) == 0) {
            const float b2v = ob2[0];
            #pragma unroll
            for (int j = 0; j < 2; ++j) {
                int r = rlist[r0 + j];
                if (r >= 0) e_atom[r] = ep[j] + b2v;
            }
        }
    }
}

// ---------------------------------------------------------------------------
__global__ __launch_bounds__(256) void energy_graph_kernel(
    const int* __restrict__ batch, const int* __restrict__ atype,
    const int* __restrict__ is_dst, const float* __restrict__ e_atom,
    const float* __restrict__ e_type, float* __restrict__ energy, int Nn)
{
    const int g = blockIdx.x;
    int lo = 0, hi = Nn;
    while (lo < hi) { int m = (lo + hi) >> 1; if (batch[m] < g) lo = m + 1; else hi = m; }
    const int start = lo;
    hi = Nn;
    while (lo < hi) { int m = (lo + hi) >> 1; if (batch[m] < g + 1) lo = m + 1; else hi = m; }
    const int end = lo;

    float s = 0.0f;
    for (int n = start + (int)threadIdx.x; n < end; n += 256)
        s += is_dst[n] ? e_atom[n] : e_type[atype[n]];
    #pragma unroll
    for (int off = 32; off; off >>= 1) s += __shfl_xor(s, off, 64);
    __shared__ float wp[4];
    if ((threadIdx.x & 63) == 0) wp[threadIdx.x >> 6] = s;
    __syncthreads();
    if (threadIdx.x == 0) energy[g] = wp[0] + wp[1] + wp[2] + wp[3];
}

// ---------------------------------------------------------------------------
extern "C" void kernel_launch(void* const* d_in, const int* in_sizes, int n_in,
                              void* d_out, int out_size, void* d_ws, size_t ws_size,
                              hipStream_t stream)
{
    const int*   atype = (const int*)  d_in[0];
    const float* pos   = (const float*)d_in[1];
    const int*   ei    = (const int*)  d_in[2];
    const int*   batch = (const int*)  d_in[3];
    const float* emb   = (const float*)d_in[4];
    const float* fw1   = (const float*)d_in[5];
    const float* fb1   = (const float*)d_in[6];
    const float* fw2   = (const float*)d_in[7];
    const float* fb2   = (const float*)d_in[8];
    const float* lin1w = (const float*)d_in[9];
    const float* lin2w = (const float*)d_in[10];
    const float* lin2b = (const float*)d_in[11];
    const float* blkw  = (const float*)d_in[12];
    const float* blkb  = (const float*)d_in[13];
    const float* ow1   = (const float*)d_in[14];
    const float* ob1   = (const float*)d_in[15];
    const float* ow2   = (const float*)d_in[16];
    const float* ob2   = (const float*)d_in[17];

    const int Nn = in_sizes[0];
    const int E  = in_sizes[2] / 2;
    const int NT = in_sizes[4] / H;
    float* energy = (float*)d_out;

    // edge segmentation geometry
    const int eblocks = (E + 1023) / 1024;
    const int bps = (eblocks + SEG - 1) / SEG;
    const int CAP = bps * 1024;
    const int SEGCAP = SEG * CAP;

    // workspace layout
    char* w = (char*)d_ws;
    int*   cnt  = (int*)w;           // [1]=dst [2]=sd ; [8..23]=seg_cnt
    int*   seg_cnt = cnt + 8;
    int*   is_src = cnt + 32;                           // N
    int*   is_dst = is_src + Nn;                        // N
    float* x    = (float*)(is_dst + Nn);                // N*H
    float* hbuf = x + (size_t)Nn * H;                   // N*H
    float* agg  = hbuf + (size_t)Nn * H;                // N*H
    int*   asrc = (int*)(agg + (size_t)Nn * H);         // SEGCAP
    int*   adst = asrc + SEGCAP;                        // SEGCAP
    float* ad   = (float*)(adst + SEGCAP);              // SEGCAP
    int*   asty = (int*)(ad + SEGCAP);                  // SEGCAP
    int*   dst_list = asty + SEGCAP;                    // N
    int*   sd_list  = dst_list + Nn;                    // N
    float* cvec = (float*)(sd_list + Nn);               // 2*H
    float* tab  = cvec + 2 * H;                         // 2*(QT+1)*H
    float* e_type = tab + 2 * (size_t)(QT + 1) * H;     // 128
    float* htype0 = e_type + 128;                       // NT*H
    float* htype1 = htype0 + (size_t)NT * H;            // NT*H
    float* e_atom = htype1 + (size_t)NT * H;            // N
    float4* pos4 = (float4*)(e_atom + Nn);              // N

    // prep roles
    const int zquads = (128 + 2 * Nn * 4) / 16;
    const int ZFB = (zquads + 255) / 256;
    const int PB  = (Nn + 255) / 256;
    const int FB  = (2 * (QT + 1) + 2 + 3) / 4;
    const int TB  = (NT + 3) / 4;
    const int H0B = (NT + 3) / 4;
    const int H1B = (NT + 3) / 4;

    prep_kernel<<<ZFB + PB + FB + TB + H0B + H1B, 256, 0, stream>>>(
        pos, pos4, Nn, (int4*)cnt, zquads,
        fw1, fb1, fw2, fb2, lin1w, lin2b, blkw, blkb, emb,
        ow1, ob1, ow2, ob2, tab, cvec, e_type, htype0, htype1, NT,
        ZFB, PB, FB, TB, H0B);

    edge_prep_kernel<<<eblocks, 256, 0, stream>>>(
        pos4, ei, atype, E, CAP, seg_cnt, asrc, adst, ad, asty, is_src, is_dst);
    compact_atoms_kernel<<<(Nn + 255) / 256, 256, 0, stream>>>(
        is_src, is_dst, Nn, cnt, dst_list, sd_list, agg);

    // ---- interaction block 0 (h comes from htype0 table) ----
    edge_scatter0_kernel<<<1024, 256, 0, stream>>>(
        seg_cnt, adst, ad, asty, tab, htype0, agg, CAP);
    update_x0_kernel<<<512, 256, 0, stream>>>(
        agg, lin2w, lin2b, blkw, blkb, x, emb, atype, dst_list, cnt + 1);

    // ---- interaction block 1 ----
    gemm_sd_kernel<<<128, 256, 0, stream>>>(
        x, lin1w + (size_t)H * H, hbuf, sd_list, cnt + 2);
    edge_scatter1_kernel<<<1024, 256, 0, stream>>>(
        seg_cnt, asrc, adst, ad, asty, is_dst,
        tab + (size_t)(QT + 1) * H, hbuf, htype1, agg, CAP);
    update_e_kernel<<<512, 256, 0, stream>>>(
        agg, lin2w + (size_t)H * H, lin2b + H, blkw + (size_t)H * H, blkb + H,
        x, ow1, ob1, ow2, ob2, e_atom, dst_list, cnt + 1);

    // ---- per-graph energy ----
    energy_graph_kernel<<<out_size, 256, 0, stream>>>(
        batch, atype, is_dst, e_atom, e_type, energy, Nn);
}